// Round 1
// baseline (2147.230 us; speedup 1.0000x reference)
//
#include <hip/hip_runtime.h>

#define HD 128
#define EIN 273      // 2*128 + 1 + 16
#define EPB 16       // edges per block (edge kernel)
#define NPB 8        // nodes per block (node-wise kernels)
#define PROP 1000

__device__ __forceinline__ float silu_f(float v) {
    return v / (1.0f + __expf(-v));
}
__device__ __forceinline__ float4 silu4(float4 v) {
    return make_float4(silu_f(v.x), silu_f(v.y), silu_f(v.z), silu_f(v.w));
}
__device__ __forceinline__ float4 ld4(const float* p) { return *(const float4*)p; }

#define FMA4(A, S, W) do { (A).x += (S)*(W).x; (A).y += (S)*(W).y; (A).z += (S)*(W).z; (A).w += (S)*(W).w; } while (0)

// ---------------- in-degree count (float, exact) ----------------
__global__ void count_kernel(const int* __restrict__ ei, float* __restrict__ cnt, int E) {
    int e = blockIdx.x * 256 + threadIdx.x;
    if (e < E) atomicAdd(&cnt[ei[e]], 1.0f);
}

// ---------------- h = x @ W(64x128) + b ----------------
__global__ __launch_bounds__(128) void emb_kernel(
    const float* __restrict__ x, const float* __restrict__ w, const float* __restrict__ b,
    float* __restrict__ h, int N)
{
    __shared__ __align__(16) float s_x[64][12];
    const int tid = threadIdx.x;
    const int n0 = blockIdx.x * NPB;
    if (tid < 64) {
        #pragma unroll
        for (int n = 0; n < NPB; ++n) {
            int nn = min(n0 + n, N - 1);
            s_x[tid][n] = x[(size_t)nn * 64 + tid];
        }
    }
    __syncthreads();
    float bias = b[tid];
    float acc[NPB];
    #pragma unroll
    for (int n = 0; n < NPB; ++n) acc[n] = bias;
    for (int k = 0; k < 64; ++k) {
        float wv = w[(size_t)k * HD + tid];
        float4 x0 = ld4(&s_x[k][0]);
        float4 x1 = ld4(&s_x[k][4]);
        acc[0] += x0.x * wv; acc[1] += x0.y * wv; acc[2] += x0.z * wv; acc[3] += x0.w * wv;
        acc[4] += x1.x * wv; acc[5] += x1.y * wv; acc[6] += x1.z * wv; acc[7] += x1.w * wv;
    }
    #pragma unroll
    for (int n = 0; n < NPB; ++n)
        if (n0 + n < N) h[(size_t)(n0 + n) * HD + tid] = acc[n];
}

// ---------------- edge model + coord model (atomics into agg / pos_agg) ----------------
__global__ __launch_bounds__(128) void edge_kernel(
    const float* __restrict__ pos, const float* __restrict__ h,
    const float* __restrict__ eattr, const int* __restrict__ ei,
    const float* __restrict__ w1, const float* __restrict__ b1,
    const float* __restrict__ w2, const float* __restrict__ b2,
    const float* __restrict__ cw1, const float* __restrict__ cb1,
    const float* __restrict__ cw2,
    float* __restrict__ agg, float* __restrict__ pos_agg, int E)
{
    __shared__ __align__(16) float s_in[EIN][20];   // transposed e_in [feat][edge]
    __shared__ __align__(16) float s_hd[HD][20];    // hidden after silu
    __shared__ float s_cd[EPB][3];
    __shared__ int   s_row[EPB], s_col[EPB];
    __shared__ float s_s[EPB];

    const int tid = threadIdx.x;
    const int e0  = blockIdx.x * EPB;
    const int j4  = (tid & 31) * 4;   // feature base (0..124)
    const int eg  = (tid >> 5) * 4;   // edge base in tile (0,4,8,12)

    if (tid < EPB) {
        int e = e0 + tid;
        bool valid = e < E;
        int ec = valid ? e : E - 1;
        int r = ei[ec], c = ei[E + ec];
        s_row[tid] = valid ? r : -1;
        s_col[tid] = c;
        float dx = pos[r*3+0] - pos[c*3+0];
        float dy = pos[r*3+1] - pos[c*3+1];
        float dz = pos[r*3+2] - pos[c*3+2];
        s_cd[tid][0] = dx; s_cd[tid][1] = dy; s_cd[tid][2] = dz;
        s_in[2*HD][tid] = dx*dx + dy*dy + dz*dz;    // radial
    }
    __syncthreads();
    // gather h[row], h[col] (coalesced 512B per edge per side)
    #pragma unroll 4
    for (int e = 0; e < EPB; ++e) {
        int r = s_row[e], c = s_col[e];
        if (r < 0) r = c;
        s_in[tid][e]      = h[(size_t)r * HD + tid];
        s_in[HD + tid][e] = h[(size_t)c * HD + tid];
    }
    // edge_attr (16 per edge, contiguous)
    {
        int i = tid, e = i >> 4, a = i & 15;
        s_in[2*HD + 1 + a][e] = eattr[(size_t)min(e0 + e, E - 1) * 16 + a];
        i = tid + 128; e = i >> 4; a = i & 15;
        s_in[2*HD + 1 + a][e] = eattr[(size_t)min(e0 + e, E - 1) * 16 + a];
    }
    __syncthreads();

    // ---- edge MLP layer 1: [273] -> [128], silu
    float4 acc[4];
    {
        float4 bb = ld4(b1 + j4);
        #pragma unroll
        for (int e = 0; e < 4; ++e) acc[e] = bb;
    }
    for (int k = 0; k < EIN; ++k) {
        float4 wv = ld4(w1 + (size_t)k * HD + j4);
        float4 xv = ld4(&s_in[k][eg]);
        FMA4(acc[0], xv.x, wv);
        FMA4(acc[1], xv.y, wv);
        FMA4(acc[2], xv.z, wv);
        FMA4(acc[3], xv.w, wv);
    }
    #pragma unroll
    for (int e = 0; e < 4; ++e) acc[e] = silu4(acc[e]);
    *(float4*)&s_hd[j4+0][eg] = make_float4(acc[0].x, acc[1].x, acc[2].x, acc[3].x);
    *(float4*)&s_hd[j4+1][eg] = make_float4(acc[0].y, acc[1].y, acc[2].y, acc[3].y);
    *(float4*)&s_hd[j4+2][eg] = make_float4(acc[0].z, acc[1].z, acc[2].z, acc[3].z);
    *(float4*)&s_hd[j4+3][eg] = make_float4(acc[0].w, acc[1].w, acc[2].w, acc[3].w);
    __syncthreads();

    // ---- edge MLP layer 2: [128] -> [128], silu -> m
    float4 m[4];
    {
        float4 bb = ld4(b2 + j4);
        #pragma unroll
        for (int e = 0; e < 4; ++e) m[e] = bb;
    }
    for (int k = 0; k < HD; ++k) {
        float4 wv = ld4(w2 + (size_t)k * HD + j4);
        float4 xv = ld4(&s_hd[k][eg]);
        FMA4(m[0], xv.x, wv);
        FMA4(m[1], xv.y, wv);
        FMA4(m[2], xv.z, wv);
        FMA4(m[3], xv.w, wv);
    }
    #pragma unroll
    for (int e = 0; e < 4; ++e) m[e] = silu4(m[e]);

    // agg += m (scatter)
    #pragma unroll
    for (int e = 0; e < 4; ++e) {
        int r = s_row[eg + e];
        if (r >= 0) {
            float* dst = &agg[(size_t)r * HD + j4];
            atomicAdd(dst + 0, m[e].x);
            atomicAdd(dst + 1, m[e].y);
            atomicAdd(dst + 2, m[e].z);
            atomicAdd(dst + 3, m[e].w);
        }
    }
    // stash m (transposed) into s_in rows 0..127 for the coord layer
    *(float4*)&s_in[j4+0][eg] = make_float4(m[0].x, m[1].x, m[2].x, m[3].x);
    *(float4*)&s_in[j4+1][eg] = make_float4(m[0].y, m[1].y, m[2].y, m[3].y);
    *(float4*)&s_in[j4+2][eg] = make_float4(m[0].z, m[1].z, m[2].z, m[3].z);
    *(float4*)&s_in[j4+3][eg] = make_float4(m[0].w, m[1].w, m[2].w, m[3].w);
    __syncthreads();

    // ---- coord model: silu(m@cw1+cb1) @ cw2 -> scalar per edge
    float4 c[4];
    {
        float4 bb = ld4(cb1 + j4);
        #pragma unroll
        for (int e = 0; e < 4; ++e) c[e] = bb;
    }
    for (int k = 0; k < HD; ++k) {
        float4 wv = ld4(cw1 + (size_t)k * HD + j4);
        float4 xv = ld4(&s_in[k][eg]);
        FMA4(c[0], xv.x, wv);
        FMA4(c[1], xv.y, wv);
        FMA4(c[2], xv.z, wv);
        FMA4(c[3], xv.w, wv);
    }
    float4 cw = ld4(cw2 + j4);
    float part[4];
    #pragma unroll
    for (int e = 0; e < 4; ++e) {
        float4 sc = silu4(c[e]);
        part[e] = sc.x*cw.x + sc.y*cw.y + sc.z*cw.z + sc.w*cw.w;
    }
    #pragma unroll
    for (int off = 1; off < 32; off <<= 1) {
        #pragma unroll
        for (int e = 0; e < 4; ++e) part[e] += __shfl_xor(part[e], off, 64);
    }
    if ((tid & 31) == 0) {
        #pragma unroll
        for (int e = 0; e < 4; ++e) s_s[eg + e] = part[e];
    }
    __syncthreads();
    if (tid < EPB * 3) {
        int el = tid / 3, d = tid - el * 3;
        int r = s_row[el];
        if (r >= 0) atomicAdd(&pos_agg[(size_t)r * 3 + d], s_cd[el][d] * s_s[el]);
    }
}

// ---------------- pos += pos_agg / max(cnt,1) ----------------
__global__ void posupd_kernel(float* __restrict__ pos, const float* __restrict__ pos_agg,
                              const float* __restrict__ cnt, int N) {
    int i = blockIdx.x * 256 + threadIdx.x;
    if (i < N * 3) {
        float cdeg = fmaxf(cnt[i / 3], 1.0f);
        pos[i] += pos_agg[i] / cdeg;
    }
}

// ---------------- node model: h += MLP([h, agg]) ----------------
__global__ __launch_bounds__(128) void node_kernel(
    float* __restrict__ h, const float* __restrict__ agg,
    const float* __restrict__ w1, const float* __restrict__ b1,
    const float* __restrict__ w2, const float* __restrict__ b2, int N)
{
    __shared__ __align__(16) float s_x[2*HD][12];
    __shared__ __align__(16) float s_t[HD][12];
    const int tid = threadIdx.x;
    const int n0 = blockIdx.x * NPB;
    #pragma unroll
    for (int n = 0; n < NPB; ++n) {
        int nn = min(n0 + n, N - 1);
        s_x[tid][n]      = h[(size_t)nn * HD + tid];
        s_x[HD + tid][n] = agg[(size_t)nn * HD + tid];
    }
    __syncthreads();
    float acc[NPB];
    {
        float bias = b1[tid];
        #pragma unroll
        for (int n = 0; n < NPB; ++n) acc[n] = bias;
    }
    for (int k = 0; k < 2*HD; ++k) {
        float wv = w1[(size_t)k * HD + tid];
        float4 x0 = ld4(&s_x[k][0]);
        float4 x1 = ld4(&s_x[k][4]);
        acc[0] += x0.x * wv; acc[1] += x0.y * wv; acc[2] += x0.z * wv; acc[3] += x0.w * wv;
        acc[4] += x1.x * wv; acc[5] += x1.y * wv; acc[6] += x1.z * wv; acc[7] += x1.w * wv;
    }
    #pragma unroll
    for (int n = 0; n < NPB; ++n) s_t[tid][n] = silu_f(acc[n]);
    __syncthreads();
    float acc2[NPB];
    {
        float bias = b2[tid];
        #pragma unroll
        for (int n = 0; n < NPB; ++n) acc2[n] = bias;
    }
    for (int k = 0; k < HD; ++k) {
        float wv = w2[(size_t)k * HD + tid];
        float4 x0 = ld4(&s_t[k][0]);
        float4 x1 = ld4(&s_t[k][4]);
        acc2[0] += x0.x * wv; acc2[1] += x0.y * wv; acc2[2] += x0.z * wv; acc2[3] += x0.w * wv;
        acc2[4] += x1.x * wv; acc2[5] += x1.y * wv; acc2[6] += x1.z * wv; acc2[7] += x1.w * wv;
    }
    #pragma unroll
    for (int n = 0; n < NPB; ++n)
        if (n0 + n < N) h[(size_t)(n0 + n) * HD + tid] = s_x[tid][n] + acc2[n];
}

// ---------------- g_enc init to encode(-inf) ----------------
__global__ void ginit_kernel(unsigned* __restrict__ g_enc, int n) {
    int i = blockIdx.x * 256 + threadIdx.x;
    if (i < n) g_enc[i] = 0x007FFFFFu;   // encode(-inf)
}

// ---------------- h @ emb_out + b, then segment_max into g_enc ----------------
__global__ __launch_bounds__(128) void embout_segmax_kernel(
    const float* __restrict__ h, const float* __restrict__ w, const float* __restrict__ b,
    const int* __restrict__ batch, unsigned* __restrict__ g_enc, int N)
{
    __shared__ __align__(16) float s_x[HD][12];
    const int tid = threadIdx.x;
    const int n0 = blockIdx.x * NPB;
    #pragma unroll
    for (int n = 0; n < NPB; ++n) {
        int nn = min(n0 + n, N - 1);
        s_x[tid][n] = h[(size_t)nn * HD + tid];
    }
    __syncthreads();
    float acc[NPB];
    {
        float bias = b[tid];
        #pragma unroll
        for (int n = 0; n < NPB; ++n) acc[n] = bias;
    }
    for (int k = 0; k < HD; ++k) {
        float wv = w[(size_t)k * HD + tid];
        float4 x0 = ld4(&s_x[k][0]);
        float4 x1 = ld4(&s_x[k][4]);
        acc[0] += x0.x * wv; acc[1] += x0.y * wv; acc[2] += x0.z * wv; acc[3] += x0.w * wv;
        acc[4] += x1.x * wv; acc[5] += x1.y * wv; acc[6] += x1.z * wv; acc[7] += x1.w * wv;
    }
    #pragma unroll
    for (int n = 0; n < NPB; ++n) {
        if (n0 + n < N) {
            unsigned u = __float_as_uint(acc[n]);
            u = (u & 0x80000000u) ? ~u : (u | 0x80000000u);
            atomicMax(&g_enc[(size_t)batch[n0 + n] * HD + tid], u);
        }
    }
}

// ---------------- decode + 2 ResBlocks ----------------
__global__ __launch_bounds__(128) void resblock_kernel(
    const unsigned* __restrict__ g_enc,
    const float* __restrict__ rw1, const float* __restrict__ rb1,
    const float* __restrict__ rw2, const float* __restrict__ rb2,
    float* __restrict__ g)
{
    __shared__ float s_g[HD];
    __shared__ float s_t[HD];
    const int b = blockIdx.x, j = threadIdx.x;
    unsigned u = g_enc[(size_t)b * HD + j];
    float v = (u & 0x80000000u) ? __uint_as_float(u & 0x7FFFFFFFu) : __uint_as_float(~u);
    s_g[j] = v;
    __syncthreads();
    for (int r = 0; r < 2; ++r) {
        float a1 = rb1[r * HD + j];
        for (int k = 0; k < HD; ++k) a1 += s_g[k] * rw1[(size_t)r * HD * HD + (size_t)k * HD + j];
        s_t[j] = silu_f(a1);
        __syncthreads();
        float a2 = rb2[r * HD + j];
        for (int k = 0; k < HD; ++k) a2 += s_t[k] * rw2[(size_t)r * HD * HD + (size_t)k * HD + j];
        __syncthreads();
        s_g[j] += a2;
        __syncthreads();
    }
    g[(size_t)b * HD + j] = s_g[j];
}

// ---------------- head: out = g @ head_w + head_b ----------------
__global__ __launch_bounds__(256) void head_kernel(
    const float* __restrict__ g, const float* __restrict__ hw, const float* __restrict__ hb,
    float* __restrict__ out)
{
    __shared__ float s_g[HD];
    const int b = blockIdx.y;
    const int p = blockIdx.x * 256 + threadIdx.x;
    if (threadIdx.x < HD) s_g[threadIdx.x] = g[(size_t)b * HD + threadIdx.x];
    __syncthreads();
    if (p >= PROP) return;
    float acc = hb[p];
    for (int k = 0; k < HD; ++k) acc += s_g[k] * hw[(size_t)k * PROP + p];
    out[(size_t)b * PROP + p] = acc;
}

extern "C" void kernel_launch(void* const* d_in, const int* in_sizes, int n_in,
                              void* d_out, int out_size, void* d_ws, size_t ws_size,
                              hipStream_t stream)
{
    const float* x        = (const float*)d_in[0];
    const float* pos_in   = (const float*)d_in[1];
    const float* eattr    = (const float*)d_in[2];
    const int*   ei       = (const int*)d_in[3];
    const int*   batch    = (const int*)d_in[4];
    const float* emb_in_w = (const float*)d_in[5];
    const float* emb_in_b = (const float*)d_in[6];
    const float* emb_out_w= (const float*)d_in[7];
    const float* emb_out_b= (const float*)d_in[8];
    const float* ew1 = (const float*)d_in[9];
    const float* eb1 = (const float*)d_in[10];
    const float* ew2 = (const float*)d_in[11];
    const float* eb2 = (const float*)d_in[12];
    const float* nw1 = (const float*)d_in[13];
    const float* nb1 = (const float*)d_in[14];
    const float* nw2 = (const float*)d_in[15];
    const float* nb2 = (const float*)d_in[16];
    const float* cw1 = (const float*)d_in[17];
    const float* cb1 = (const float*)d_in[18];
    const float* cw2 = (const float*)d_in[19];
    const float* rw1 = (const float*)d_in[20];
    const float* rb1 = (const float*)d_in[21];
    const float* rw2 = (const float*)d_in[22];
    const float* rb2 = (const float*)d_in[23];
    const float* hw  = (const float*)d_in[24];
    const float* hb  = (const float*)d_in[25];
    float* out = (float*)d_out;

    const int N = in_sizes[0] / 64;     // 20000
    const int E = in_sizes[2] / 16;     // 160000
    const int B = out_size / PROP;      // 1024

    // workspace carve-up (~22.1 MB total)
    float* wsf = (float*)d_ws;
    float*    pos_cur = wsf;              wsf += (size_t)N * 3;
    float*    pos_agg = wsf;              wsf += (size_t)N * 3;
    float*    cnt     = wsf;              wsf += N;
    float*    h       = wsf;              wsf += (size_t)N * HD;
    float*    agg     = wsf;              wsf += (size_t)N * HD;
    unsigned* g_enc   = (unsigned*)wsf;   wsf += (size_t)B * HD;
    float*    g       = wsf;              wsf += (size_t)B * HD;

    hipMemcpyAsync(pos_cur, pos_in, (size_t)N * 3 * sizeof(float),
                   hipMemcpyDeviceToDevice, stream);
    hipMemsetAsync(cnt, 0, (size_t)N * sizeof(float), stream);
    count_kernel<<<(E + 255) / 256, 256, 0, stream>>>(ei, cnt, E);
    emb_kernel<<<(N + NPB - 1) / NPB, 128, 0, stream>>>(x, emb_in_w, emb_in_b, h, N);

    for (int l = 0; l < 4; ++l) {
        hipMemsetAsync(agg, 0, (size_t)N * HD * sizeof(float), stream);
        hipMemsetAsync(pos_agg, 0, (size_t)N * 3 * sizeof(float), stream);
        edge_kernel<<<(E + EPB - 1) / EPB, 128, 0, stream>>>(
            pos_cur, h, eattr, ei,
            ew1 + (size_t)l * EIN * HD, eb1 + (size_t)l * HD,
            ew2 + (size_t)l * HD * HD,  eb2 + (size_t)l * HD,
            cw1 + (size_t)l * HD * HD,  cb1 + (size_t)l * HD,
            cw2 + (size_t)l * HD,
            agg, pos_agg, E);
        posupd_kernel<<<(N * 3 + 255) / 256, 256, 0, stream>>>(pos_cur, pos_agg, cnt, N);
        node_kernel<<<(N + NPB - 1) / NPB, 128, 0, stream>>>(
            h, agg,
            nw1 + (size_t)l * 2 * HD * HD, nb1 + (size_t)l * HD,
            nw2 + (size_t)l * HD * HD,     nb2 + (size_t)l * HD, N);
    }

    ginit_kernel<<<(B * HD + 255) / 256, 256, 0, stream>>>(g_enc, B * HD);
    embout_segmax_kernel<<<(N + NPB - 1) / NPB, 128, 0, stream>>>(
        h, emb_out_w, emb_out_b, batch, g_enc, N);
    resblock_kernel<<<B, 128, 0, stream>>>(g_enc, rw1, rb1, rw2, rb2, g);
    head_kernel<<<dim3((PROP + 255) / 256, B), 256, 0, stream>>>(g, hw, hb, out);
}

// Round 2
// 1748.164 us; speedup vs baseline: 1.2283x; 1.2283x over previous
//
#include <hip/hip_runtime.h>

#define HD 128
#define PROP 1000
#define KPAD 288          // padded edge-MLP input K (273 -> 9*32)
#define EB   64           // edges per block
#define LDE  640          // e_in LDS row stride bytes (multiple of 128B for swizzle closure)
#define LDM  256          // m1/m LDS row stride bytes
#define NPB  8            // nodes per block (node-wise kernels)

typedef float f32x4 __attribute__((ext_vector_type(4)));
typedef short s16x8 __attribute__((ext_vector_type(8)));

__device__ __forceinline__ float silu_f(float v) { return v / (1.0f + __expf(-v)); }
__device__ __forceinline__ unsigned short f2bf(float f) {
    union { float f; unsigned u; } v; v.f = f;
    unsigned r = v.u + 0x7FFFu + ((v.u >> 16) & 1u);   // RNE
    return (unsigned short)(r >> 16);
}
__device__ __forceinline__ unsigned pk2(float a, float b) {
    return (unsigned)f2bf(a) | ((unsigned)f2bf(b) << 16);
}
__device__ __forceinline__ float4 ld4(const float* p) { return *(const float4*)p; }

// ---------------- in-degree count ----------------
__global__ void count_kernel(const int* __restrict__ ei, float* __restrict__ cnt, int E) {
    int e = blockIdx.x * 256 + threadIdx.x;
    if (e < E) atomicAdd(&cnt[ei[e]], 1.0f);
}

// ---------------- weight prep: Wt[l][o][k] = bf16(w[l][k][o]) with K remap/pad ----------------
__global__ void prep_w1t(const float* __restrict__ w1, unsigned short* __restrict__ wt1) {
    int idx = blockIdx.x * 256 + threadIdx.x;
    if (idx >= 4 * HD * KPAD) return;
    int k = idx % KPAD; int rem = idx / KPAD; int o = rem % HD; int l = rem / HD;
    // LDS K layout: [h_row 0..127][h_col 128..255][eattr 256..271][radial 272][zeros...]
    int ksrc;
    if (k < 256)      ksrc = k;
    else if (k < 272) ksrc = 257 + (k - 256);
    else if (k == 272) ksrc = 256;
    else               ksrc = -1;
    float v = (ksrc >= 0) ? w1[((size_t)l * 273 + ksrc) * HD + o] : 0.0f;
    wt1[idx] = f2bf(v);
}
__global__ void prep_sqt(const float* __restrict__ w, unsigned short* __restrict__ wt) {
    int idx = blockIdx.x * 256 + threadIdx.x;
    if (idx >= 4 * HD * HD) return;
    int k = idx & 127; int o = (idx >> 7) & 127; int l = idx >> 14;
    wt[idx] = f2bf(w[((size_t)l * HD + k) * HD + o]);
}

// ---------------- h = x @ W(64x128) + b ----------------
__global__ __launch_bounds__(128) void emb_kernel(
    const float* __restrict__ x, const float* __restrict__ w, const float* __restrict__ b,
    float* __restrict__ h, int N)
{
    __shared__ __align__(16) float s_x[64][12];
    const int tid = threadIdx.x;
    const int n0 = blockIdx.x * NPB;
    if (tid < 64) {
        #pragma unroll
        for (int n = 0; n < NPB; ++n) {
            int nn = min(n0 + n, N - 1);
            s_x[tid][n] = x[(size_t)nn * 64 + tid];
        }
    }
    __syncthreads();
    float bias = b[tid];
    float acc[NPB];
    #pragma unroll
    for (int n = 0; n < NPB; ++n) acc[n] = bias;
    for (int k = 0; k < 64; ++k) {
        float wv = w[(size_t)k * HD + tid];
        float4 x0 = ld4(&s_x[k][0]);
        float4 x1 = ld4(&s_x[k][4]);
        acc[0] += x0.x * wv; acc[1] += x0.y * wv; acc[2] += x0.z * wv; acc[3] += x0.w * wv;
        acc[4] += x1.x * wv; acc[5] += x1.y * wv; acc[6] += x1.z * wv; acc[7] += x1.w * wv;
    }
    #pragma unroll
    for (int n = 0; n < NPB; ++n)
        if (n0 + n < N) h[(size_t)(n0 + n) * HD + tid] = acc[n];
}

// ---------------- edge + coord models via MFMA ----------------
// Block: 256 threads (4 waves), EB=64 edges. A = Wt (global bf16 [out][K]), B = features in LDS.
__global__ __launch_bounds__(256) void edge_mfma_kernel(
    const float* __restrict__ pos, const float* __restrict__ h,
    const float* __restrict__ eattr, const int* __restrict__ ei,
    const unsigned short* __restrict__ wt1, const float* __restrict__ b1,
    const unsigned short* __restrict__ wt2, const float* __restrict__ b2,
    const unsigned short* __restrict__ cwt1, const float* __restrict__ cb1,
    const float* __restrict__ cw2,
    float* __restrict__ agg, float* __restrict__ pos_agg, int E)
{
    __shared__ __align__(16) char s_ein[EB * LDE];   // e_in bf16 [64][288e] (later aliased by m [64][128e])
    __shared__ __align__(16) char s_m1[EB * LDM];    // m1 bf16 [64][128e]
    __shared__ float s_cd[EB][3];
    __shared__ int s_row[EB], s_col[EB];

    const int tid  = threadIdx.x;
    const int lane = tid & 63;
    const int wv   = tid >> 6;        // 0..3
    const int lr   = lane & 15;
    const int kg   = lane >> 4;       // 0..3
    const int e0   = blockIdx.x * EB;

    // ---- phase A: indices, coord_diff, radial, zero-pad, eattr ----
    if (tid < EB) {
        int e = e0 + tid;
        bool valid = e < E;
        int ec = valid ? e : E - 1;
        int r = ei[ec], c = ei[E + ec];
        s_row[tid] = valid ? r : -1;
        s_col[tid] = c;
        float dx = pos[r*3+0] - pos[c*3+0];
        float dy = pos[r*3+1] - pos[c*3+1];
        float dz = pos[r*3+2] - pos[c*3+2];
        s_cd[tid][0] = dx; s_cd[tid][1] = dy; s_cd[tid][2] = dz;
        float rad = dx*dx + dy*dy + dz*dz;
        char* rowp = s_ein + tid * LDE;
        int sw = (tid & 7) << 4;
        *(uint2*)(rowp + (544 ^ sw)) = make_uint2(0u, 0u);   // elems 272..275
        *(uint2*)(rowp + (552 ^ sw)) = make_uint2(0u, 0u);   // 276..279
        *(uint2*)(rowp + (560 ^ sw)) = make_uint2(0u, 0u);   // 280..283
        *(uint2*)(rowp + (568 ^ sw)) = make_uint2(0u, 0u);   // 284..287
        *(unsigned short*)(rowp + (544 ^ sw)) = f2bf(rad);   // radial at elem 272
    }
    {   // eattr -> elems 256..271
        int e = tid >> 2, q = tid & 3;
        int ec = min(e0 + e, E - 1);
        float4 v = ld4(eattr + (size_t)ec * 16 + q * 4);
        int sw = (e & 7) << 4;
        *(uint2*)(s_ein + e * LDE + ((512 + q * 8) ^ sw)) = make_uint2(pk2(v.x, v.y), pk2(v.z, v.w));
    }
    __syncthreads();
    // ---- phase B: gather h[row], h[col] ----
    {
        int lane32 = tid & 31, g = tid >> 5;
        #pragma unroll 4
        for (int p = 0; p < 16; ++p) {
            int gi = p * 8 + g;                // 0..127
            int e = gi >> 1, side = gi & 1;
            int node = side ? s_col[e] : s_row[e];
            if (node < 0) node = s_col[e];
            float4 v = ld4(h + (size_t)node * HD + lane32 * 4);
            int sw = (e & 7) << 4;
            *(uint2*)(s_ein + e * LDE + ((side * 256 + lane32 * 8) ^ sw)) =
                make_uint2(pk2(v.x, v.y), pk2(v.z, v.w));
        }
    }
    __syncthreads();

    const int we  = wv * 16;
    const int el  = we + lr;            // this lane's edge (as C column)
    const int esw = (el & 7) << 4;

    // ---- GEMM1: m1 = silu(e_in @ W1 + b1), K=288 ----
    f32x4 acc[8];
    #pragma unroll
    for (int mf = 0; mf < 8; ++mf) acc[mf] = (f32x4){0.f, 0.f, 0.f, 0.f};
    {
        const char* brow = s_ein + el * LDE;
        for (int ks = 0; ks < 9; ++ks) {
            s16x8 b = *(const s16x8*)(brow + ((ks * 64 + kg * 16) ^ esw));
            #pragma unroll
            for (int mf = 0; mf < 8; ++mf) {
                s16x8 a = *(const s16x8*)(wt1 + (size_t)(mf * 16 + lr) * KPAD + ks * 32 + kg * 8);
                acc[mf] = __builtin_amdgcn_mfma_f32_16x16x32_bf16(a, b, acc[mf], 0, 0, 0);
            }
        }
        char* mrow = s_m1 + el * LDM;
        #pragma unroll
        for (int mf = 0; mf < 8; ++mf) {
            f32x4 bb = *(const f32x4*)(b1 + mf * 16 + kg * 4);
            float v0 = silu_f(acc[mf][0] + bb[0]);
            float v1 = silu_f(acc[mf][1] + bb[1]);
            float v2 = silu_f(acc[mf][2] + bb[2]);
            float v3 = silu_f(acc[mf][3] + bb[3]);
            *(uint2*)(mrow + ((mf * 32 + kg * 8) ^ esw)) = make_uint2(pk2(v0, v1), pk2(v2, v3));
        }
    }
    __syncthreads();

    // ---- GEMM2: m = silu(m1 @ W2 + b2), K=128; scatter agg += m ----
    #pragma unroll
    for (int mf = 0; mf < 8; ++mf) acc[mf] = (f32x4){0.f, 0.f, 0.f, 0.f};
    {
        const char* brow = s_m1 + el * LDM;
        for (int ks = 0; ks < 4; ++ks) {
            s16x8 b = *(const s16x8*)(brow + ((ks * 64 + kg * 16) ^ esw));
            #pragma unroll
            for (int mf = 0; mf < 8; ++mf) {
                s16x8 a = *(const s16x8*)(wt2 + (size_t)(mf * 16 + lr) * HD + ks * 32 + kg * 8);
                acc[mf] = __builtin_amdgcn_mfma_f32_16x16x32_bf16(a, b, acc[mf], 0, 0, 0);
            }
        }
        int r = s_row[el];
        char* mrow = s_ein + el * LDM;   // m aliases e_in region (all e_in reads completed)
        #pragma unroll
        for (int mf = 0; mf < 8; ++mf) {
            f32x4 bb = *(const f32x4*)(b2 + mf * 16 + kg * 4);
            float v0 = silu_f(acc[mf][0] + bb[0]);
            float v1 = silu_f(acc[mf][1] + bb[1]);
            float v2 = silu_f(acc[mf][2] + bb[2]);
            float v3 = silu_f(acc[mf][3] + bb[3]);
            if (r >= 0) {
                float* dst = &agg[(size_t)r * HD + mf * 16 + kg * 4];
                atomicAdd(dst + 0, v0); atomicAdd(dst + 1, v1);
                atomicAdd(dst + 2, v2); atomicAdd(dst + 3, v3);
            }
            *(uint2*)(mrow + ((mf * 32 + kg * 8) ^ esw)) = make_uint2(pk2(v0, v1), pk2(v2, v3));
        }
    }
    __syncthreads();

    // ---- GEMM3: s = (silu(m @ CW1 + cb1)) @ cw2 ; pos_agg += coord_diff * s ----
    #pragma unroll
    for (int mf = 0; mf < 8; ++mf) acc[mf] = (f32x4){0.f, 0.f, 0.f, 0.f};
    {
        const char* brow = s_ein + el * LDM;
        for (int ks = 0; ks < 4; ++ks) {
            s16x8 b = *(const s16x8*)(brow + ((ks * 64 + kg * 16) ^ esw));
            #pragma unroll
            for (int mf = 0; mf < 8; ++mf) {
                s16x8 a = *(const s16x8*)(cwt1 + (size_t)(mf * 16 + lr) * HD + ks * 32 + kg * 8);
                acc[mf] = __builtin_amdgcn_mfma_f32_16x16x32_bf16(a, b, acc[mf], 0, 0, 0);
            }
        }
        float part = 0.f;
        #pragma unroll
        for (int mf = 0; mf < 8; ++mf) {
            f32x4 bb = *(const f32x4*)(cb1 + mf * 16 + kg * 4);
            f32x4 cw = *(const f32x4*)(cw2 + mf * 16 + kg * 4);
            part += silu_f(acc[mf][0] + bb[0]) * cw[0];
            part += silu_f(acc[mf][1] + bb[1]) * cw[1];
            part += silu_f(acc[mf][2] + bb[2]) * cw[2];
            part += silu_f(acc[mf][3] + bb[3]) * cw[3];
        }
        part += __shfl_xor(part, 16, 64);
        part += __shfl_xor(part, 32, 64);
        if (lane < 16) {
            int e = we + lane;
            int r = s_row[e];
            if (r >= 0) {
                atomicAdd(&pos_agg[(size_t)r * 3 + 0], s_cd[e][0] * part);
                atomicAdd(&pos_agg[(size_t)r * 3 + 1], s_cd[e][1] * part);
                atomicAdd(&pos_agg[(size_t)r * 3 + 2], s_cd[e][2] * part);
            }
        }
    }
}

// ---------------- pos += pos_agg / max(cnt,1) ----------------
__global__ void posupd_kernel(float* __restrict__ pos, const float* __restrict__ pos_agg,
                              const float* __restrict__ cnt, int N) {
    int i = blockIdx.x * 256 + threadIdx.x;
    if (i < N * 3) {
        float cdeg = fmaxf(cnt[i / 3], 1.0f);
        pos[i] += pos_agg[i] / cdeg;
    }
}

// ---------------- node model: h += MLP([h, agg]) ----------------
__global__ __launch_bounds__(128) void node_kernel(
    float* __restrict__ h, const float* __restrict__ agg,
    const float* __restrict__ w1, const float* __restrict__ b1,
    const float* __restrict__ w2, const float* __restrict__ b2, int N)
{
    __shared__ __align__(16) float s_x[2*HD][12];
    __shared__ __align__(16) float s_t[HD][12];
    const int tid = threadIdx.x;
    const int n0 = blockIdx.x * NPB;
    #pragma unroll
    for (int n = 0; n < NPB; ++n) {
        int nn = min(n0 + n, N - 1);
        s_x[tid][n]      = h[(size_t)nn * HD + tid];
        s_x[HD + tid][n] = agg[(size_t)nn * HD + tid];
    }
    __syncthreads();
    float acc[NPB];
    {
        float bias = b1[tid];
        #pragma unroll
        for (int n = 0; n < NPB; ++n) acc[n] = bias;
    }
    for (int k = 0; k < 2*HD; ++k) {
        float wv = w1[(size_t)k * HD + tid];
        float4 x0 = ld4(&s_x[k][0]);
        float4 x1 = ld4(&s_x[k][4]);
        acc[0] += x0.x * wv; acc[1] += x0.y * wv; acc[2] += x0.z * wv; acc[3] += x0.w * wv;
        acc[4] += x1.x * wv; acc[5] += x1.y * wv; acc[6] += x1.z * wv; acc[7] += x1.w * wv;
    }
    #pragma unroll
    for (int n = 0; n < NPB; ++n) s_t[tid][n] = silu_f(acc[n]);
    __syncthreads();
    float acc2[NPB];
    {
        float bias = b2[tid];
        #pragma unroll
        for (int n = 0; n < NPB; ++n) acc2[n] = bias;
    }
    for (int k = 0; k < HD; ++k) {
        float wv = w2[(size_t)k * HD + tid];
        float4 x0 = ld4(&s_t[k][0]);
        float4 x1 = ld4(&s_t[k][4]);
        acc2[0] += x0.x * wv; acc2[1] += x0.y * wv; acc2[2] += x0.z * wv; acc2[3] += x0.w * wv;
        acc2[4] += x1.x * wv; acc2[5] += x1.y * wv; acc2[6] += x1.z * wv; acc2[7] += x1.w * wv;
    }
    #pragma unroll
    for (int n = 0; n < NPB; ++n)
        if (n0 + n < N) h[(size_t)(n0 + n) * HD + tid] = s_x[tid][n] + acc2[n];
}

// ---------------- g_enc init to encode(-inf) ----------------
__global__ void ginit_kernel(unsigned* __restrict__ g_enc, int n) {
    int i = blockIdx.x * 256 + threadIdx.x;
    if (i < n) g_enc[i] = 0x007FFFFFu;
}

// ---------------- h @ emb_out + b, segment_max into g_enc ----------------
__global__ __launch_bounds__(128) void embout_segmax_kernel(
    const float* __restrict__ h, const float* __restrict__ w, const float* __restrict__ b,
    const int* __restrict__ batch, unsigned* __restrict__ g_enc, int N)
{
    __shared__ __align__(16) float s_x[HD][12];
    const int tid = threadIdx.x;
    const int n0 = blockIdx.x * NPB;
    #pragma unroll
    for (int n = 0; n < NPB; ++n) {
        int nn = min(n0 + n, N - 1);
        s_x[tid][n] = h[(size_t)nn * HD + tid];
    }
    __syncthreads();
    float acc[NPB];
    {
        float bias = b[tid];
        #pragma unroll
        for (int n = 0; n < NPB; ++n) acc[n] = bias;
    }
    for (int k = 0; k < HD; ++k) {
        float wv = w[(size_t)k * HD + tid];
        float4 x0 = ld4(&s_x[k][0]);
        float4 x1 = ld4(&s_x[k][4]);
        acc[0] += x0.x * wv; acc[1] += x0.y * wv; acc[2] += x0.z * wv; acc[3] += x0.w * wv;
        acc[4] += x1.x * wv; acc[5] += x1.y * wv; acc[6] += x1.z * wv; acc[7] += x1.w * wv;
    }
    #pragma unroll
    for (int n = 0; n < NPB; ++n) {
        if (n0 + n < N) {
            unsigned u = __float_as_uint(acc[n]);
            u = (u & 0x80000000u) ? ~u : (u | 0x80000000u);
            atomicMax(&g_enc[(size_t)batch[n0 + n] * HD + tid], u);
        }
    }
}

// ---------------- decode + 2 ResBlocks ----------------
__global__ __launch_bounds__(128) void resblock_kernel(
    const unsigned* __restrict__ g_enc,
    const float* __restrict__ rw1, const float* __restrict__ rb1,
    const float* __restrict__ rw2, const float* __restrict__ rb2,
    float* __restrict__ g)
{
    __shared__ float s_g[HD];
    __shared__ float s_t[HD];
    const int b = blockIdx.x, j = threadIdx.x;
    unsigned u = g_enc[(size_t)b * HD + j];
    float v = (u & 0x80000000u) ? __uint_as_float(u & 0x7FFFFFFFu) : __uint_as_float(~u);
    s_g[j] = v;
    __syncthreads();
    for (int r = 0; r < 2; ++r) {
        float a1 = rb1[r * HD + j];
        for (int k = 0; k < HD; ++k) a1 += s_g[k] * rw1[(size_t)r * HD * HD + (size_t)k * HD + j];
        s_t[j] = silu_f(a1);
        __syncthreads();
        float a2 = rb2[r * HD + j];
        for (int k = 0; k < HD; ++k) a2 += s_t[k] * rw2[(size_t)r * HD * HD + (size_t)k * HD + j];
        __syncthreads();
        s_g[j] += a2;
        __syncthreads();
    }
    g[(size_t)b * HD + j] = s_g[j];
}

// ---------------- head ----------------
__global__ __launch_bounds__(256) void head_kernel(
    const float* __restrict__ g, const float* __restrict__ hw, const float* __restrict__ hb,
    float* __restrict__ out)
{
    __shared__ float s_g[HD];
    const int b = blockIdx.y;
    const int p = blockIdx.x * 256 + threadIdx.x;
    if (threadIdx.x < HD) s_g[threadIdx.x] = g[(size_t)b * HD + threadIdx.x];
    __syncthreads();
    if (p >= PROP) return;
    float acc = hb[p];
    for (int k = 0; k < HD; ++k) acc += s_g[k] * hw[(size_t)k * PROP + p];
    out[(size_t)b * PROP + p] = acc;
}

extern "C" void kernel_launch(void* const* d_in, const int* in_sizes, int n_in,
                              void* d_out, int out_size, void* d_ws, size_t ws_size,
                              hipStream_t stream)
{
    const float* x        = (const float*)d_in[0];
    const float* pos_in   = (const float*)d_in[1];
    const float* eattr    = (const float*)d_in[2];
    const int*   ei       = (const int*)d_in[3];
    const int*   batch    = (const int*)d_in[4];
    const float* emb_in_w = (const float*)d_in[5];
    const float* emb_in_b = (const float*)d_in[6];
    const float* emb_out_w= (const float*)d_in[7];
    const float* emb_out_b= (const float*)d_in[8];
    const float* ew1 = (const float*)d_in[9];
    const float* eb1 = (const float*)d_in[10];
    const float* ew2 = (const float*)d_in[11];
    const float* eb2 = (const float*)d_in[12];
    const float* nw1 = (const float*)d_in[13];
    const float* nb1 = (const float*)d_in[14];
    const float* nw2 = (const float*)d_in[15];
    const float* nb2 = (const float*)d_in[16];
    const float* cw1 = (const float*)d_in[17];
    const float* cb1 = (const float*)d_in[18];
    const float* cw2 = (const float*)d_in[19];
    const float* rw1 = (const float*)d_in[20];
    const float* rb1 = (const float*)d_in[21];
    const float* rw2 = (const float*)d_in[22];
    const float* rb2 = (const float*)d_in[23];
    const float* hw  = (const float*)d_in[24];
    const float* hb  = (const float*)d_in[25];
    float* out = (float*)d_out;

    const int N = in_sizes[0] / 64;     // 20000
    const int E = in_sizes[2] / 16;     // 160000
    const int B = out_size / PROP;      // 1024

    float* wsf = (float*)d_ws;
    float*    pos_cur = wsf;              wsf += (size_t)N * 3;
    float*    pos_agg = wsf;              wsf += (size_t)N * 3;
    float*    cnt     = wsf;              wsf += N;
    float*    h       = wsf;              wsf += (size_t)N * HD;
    float*    agg     = wsf;              wsf += (size_t)N * HD;
    unsigned* g_enc   = (unsigned*)wsf;   wsf += (size_t)B * HD;
    float*    g       = wsf;              wsf += (size_t)B * HD;
    // bf16 transposed weights (16B-aligned: offset so far is a multiple of 16)
    unsigned short* wt1  = (unsigned short*)wsf;   // [4][128][288]
    unsigned short* wt2  = wt1 + (size_t)4 * HD * KPAD;   // [4][128][128]
    unsigned short* cwt1 = wt2 + (size_t)4 * HD * HD;     // [4][128][128]

    prep_w1t<<<(4 * HD * KPAD + 255) / 256, 256, 0, stream>>>(ew1, wt1);
    prep_sqt<<<(4 * HD * HD + 255) / 256, 256, 0, stream>>>(ew2, wt2);
    prep_sqt<<<(4 * HD * HD + 255) / 256, 256, 0, stream>>>(cw1, cwt1);

    hipMemcpyAsync(pos_cur, pos_in, (size_t)N * 3 * sizeof(float),
                   hipMemcpyDeviceToDevice, stream);
    hipMemsetAsync(cnt, 0, (size_t)N * sizeof(float), stream);
    count_kernel<<<(E + 255) / 256, 256, 0, stream>>>(ei, cnt, E);
    emb_kernel<<<(N + NPB - 1) / NPB, 128, 0, stream>>>(x, emb_in_w, emb_in_b, h, N);

    for (int l = 0; l < 4; ++l) {
        hipMemsetAsync(agg, 0, (size_t)N * HD * sizeof(float), stream);
        hipMemsetAsync(pos_agg, 0, (size_t)N * 3 * sizeof(float), stream);
        edge_mfma_kernel<<<(E + EB - 1) / EB, 256, 0, stream>>>(
            pos_cur, h, eattr, ei,
            wt1 + (size_t)l * HD * KPAD, eb1 + (size_t)l * HD,
            wt2 + (size_t)l * HD * HD,   eb2 + (size_t)l * HD,
            cwt1 + (size_t)l * HD * HD,  cb1 + (size_t)l * HD,
            cw2 + (size_t)l * HD,
            agg, pos_agg, E);
        posupd_kernel<<<(N * 3 + 255) / 256, 256, 0, stream>>>(pos_cur, pos_agg, cnt, N);
        node_kernel<<<(N + NPB - 1) / NPB, 128, 0, stream>>>(
            h, agg,
            nw1 + (size_t)l * 2 * HD * HD, nb1 + (size_t)l * HD,
            nw2 + (size_t)l * HD * HD,     nb2 + (size_t)l * HD, N);
    }

    ginit_kernel<<<(B * HD + 255) / 256, 256, 0, stream>>>(g_enc, B * HD);
    embout_segmax_kernel<<<(N + NPB - 1) / NPB, 128, 0, stream>>>(
        h, emb_out_w, emb_out_b, batch, g_enc, N);
    resblock_kernel<<<B, 128, 0, stream>>>(g_enc, rw1, rb1, rw2, rb2, g);
    head_kernel<<<dim3((PROP + 255) / 256, B), 256, 0, stream>>>(g, hw, hb, out);
}

// Round 3
// 889.356 us; speedup vs baseline: 2.4144x; 1.9657x over previous
//
#include <hip/hip_runtime.h>

#define HD 128
#define PROP 1000
#define EB   64           // edges per block
#define LDA  80           // attr k-slice LDS row stride (bytes)
#define LDM  256          // m1/m LDS row stride (bytes)
#define NPB  8            // nodes per block (VALU node-wise kernels)

typedef float f32x4 __attribute__((ext_vector_type(4)));
typedef short s16x8 __attribute__((ext_vector_type(8)));

__device__ __forceinline__ float silu_f(float v) { return v / (1.0f + __expf(-v)); }
__device__ __forceinline__ unsigned short f2bf(float f) {
    union { float f; unsigned u; } v; v.f = f;
    unsigned r = v.u + 0x7FFFu + ((v.u >> 16) & 1u);   // RNE
    return (unsigned short)(r >> 16);
}
__device__ __forceinline__ unsigned pk2(float a, float b) {
    return (unsigned)f2bf(a) | ((unsigned)f2bf(b) << 16);
}
__device__ __forceinline__ float bf2f(unsigned s) { return __uint_as_float(s << 16); }
__device__ __forceinline__ float4 ld4(const float* p) { return *(const float4*)p; }

// ================= CSR build =================
__global__ void counti_kernel(const int* __restrict__ ei, int* __restrict__ cnt, int E) {
    int e = blockIdx.x * 256 + threadIdx.x;
    if (e < E) atomicAdd(&cnt[ei[e]], 1);
}

__global__ __launch_bounds__(1024) void scan_kernel(
    const int* __restrict__ cnt, int* __restrict__ rp, int* __restrict__ wp, int N)
{
    __shared__ int s[1024];
    __shared__ int carry;
    const int tid = threadIdx.x;
    if (tid == 0) carry = 0;
    __syncthreads();
    for (int base = 0; base < N; base += 1024) {
        int v = (base + tid < N) ? cnt[base + tid] : 0;
        s[tid] = v;
        __syncthreads();
        for (int off = 1; off < 1024; off <<= 1) {
            int t = (tid >= off) ? s[tid - off] : 0;
            __syncthreads();
            s[tid] += t;
            __syncthreads();
        }
        int excl = carry + s[tid] - v;
        if (base + tid < N) { rp[base + tid] = excl; wp[base + tid] = excl; }
        __syncthreads();
        if (tid == 0) carry += s[1023];
        __syncthreads();
    }
    if (tid == 0) rp[N] = carry;
}

__global__ void scatter_kernel(const int* __restrict__ ei, int* __restrict__ wp,
                               int* __restrict__ perm, int E) {
    int e = blockIdx.x * 256 + threadIdx.x;
    if (e < E) {
        int p = atomicAdd(&wp[ei[e]], 1);
        perm[p] = e;
    }
}

// ================= weight prep =================
// w1nc_t[l][o2<256][k<128]: o2<128 -> ew1 rows 0..127 ; o2>=128 -> rows 128..255
__global__ void prep_w1nc(const float* __restrict__ ew1, unsigned short* __restrict__ dst) {
    int idx = blockIdx.x * 256 + threadIdx.x;
    if (idx >= 4 * 256 * 128) return;
    int k = idx & 127, o2 = (idx >> 7) & 255, l = idx >> 15;
    dst[idx] = f2bf(ew1[((size_t)l * 273 + k + ((o2 >> 7) << 7)) * 128 + (o2 & 127)]);
}
// wattr_t[l][o][k<32]: k<16 -> eattr rows (257+k); k==16 -> radial row 256; else 0
__global__ void prep_wattr(const float* __restrict__ ew1, unsigned short* __restrict__ dst) {
    int idx = blockIdx.x * 256 + threadIdx.x;
    if (idx >= 4 * 128 * 32) return;
    int k = idx & 31, o = (idx >> 5) & 127, l = idx >> 12;
    int ksrc = (k < 16) ? (257 + k) : (k == 16 ? 256 : -1);
    float v = (ksrc >= 0) ? ew1[((size_t)l * 273 + ksrc) * 128 + o] : 0.0f;
    dst[idx] = f2bf(v);
}
// generic transpose: src [4][K][128] -> dst [4][128][K]
__global__ void prep_t(const float* __restrict__ src, unsigned short* __restrict__ dst, int K) {
    int idx = blockIdx.x * 256 + threadIdx.x;
    if (idx >= 4 * 128 * K) return;
    int k = idx % K, o = (idx / K) & 127, l = idx / (K * 128);
    dst[idx] = f2bf(src[((size_t)l * K + k) * 128 + o]);
}

// ================= h = x @ W(64x128) + b =================
__global__ __launch_bounds__(128) void emb_kernel(
    const float* __restrict__ x, const float* __restrict__ w, const float* __restrict__ b,
    float* __restrict__ h, int N)
{
    __shared__ __align__(16) float s_x[64][12];
    const int tid = threadIdx.x;
    const int n0 = blockIdx.x * NPB;
    if (tid < 64) {
        #pragma unroll
        for (int n = 0; n < NPB; ++n) {
            int nn = min(n0 + n, N - 1);
            s_x[tid][n] = x[(size_t)nn * 64 + tid];
        }
    }
    __syncthreads();
    float bias = b[tid];
    float acc[NPB];
    #pragma unroll
    for (int n = 0; n < NPB; ++n) acc[n] = bias;
    for (int k = 0; k < 64; ++k) {
        float wv = w[(size_t)k * HD + tid];
        float4 x0 = ld4(&s_x[k][0]);
        float4 x1 = ld4(&s_x[k][4]);
        acc[0] += x0.x * wv; acc[1] += x0.y * wv; acc[2] += x0.z * wv; acc[3] += x0.w * wv;
        acc[4] += x1.x * wv; acc[5] += x1.y * wv; acc[6] += x1.z * wv; acc[7] += x1.w * wv;
    }
    #pragma unroll
    for (int n = 0; n < NPB; ++n)
        if (n0 + n < N) h[(size_t)(n0 + n) * HD + tid] = acc[n];
}

// ================= node_pre: apre[n][0:128]=h@W1row+b1 ; [128:256]=h@W1col (bf16) =================
__global__ __launch_bounds__(256) void node_pre_kernel(
    const float* __restrict__ h, const unsigned short* __restrict__ w1nc,
    const float* __restrict__ b1, unsigned short* __restrict__ apre, int N)
{
    __shared__ __align__(16) char s_h[64 * 256];   // bf16 [64 nodes][128 feats], swizzled
    const int tid = threadIdx.x;
    const int lane = tid & 63, wv = tid >> 6, lr = lane & 15, kg = lane >> 4;
    const int n0 = blockIdx.x * 64;
    {
        int node = tid >> 2, q = tid & 3;
        int nn = min(n0 + node, N - 1);
        int sw = (node & 7) << 4;
        #pragma unroll
        for (int it = 0; it < 8; ++it) {
            int c = q * 32 + it * 4;
            float4 v = ld4(h + (size_t)nn * HD + c);
            *(uint2*)(s_h + node * 256 + ((c * 2) ^ sw)) = make_uint2(pk2(v.x, v.y), pk2(v.z, v.w));
        }
    }
    __syncthreads();
    const int el = wv * 16 + lr;
    const int esw = (el & 7) << 4;
    const int nd = n0 + el;
    f32x4 acc[16];
    #pragma unroll
    for (int mf = 0; mf < 16; ++mf) acc[mf] = (f32x4){0.f, 0.f, 0.f, 0.f};
    const char* brow = s_h + el * 256;
    for (int ks = 0; ks < 4; ++ks) {
        s16x8 b = *(const s16x8*)(brow + ((ks * 64 + kg * 16) ^ esw));
        #pragma unroll
        for (int mf = 0; mf < 16; ++mf) {
            s16x8 a = *(const s16x8*)(w1nc + (size_t)(mf * 16 + lr) * 128 + ks * 32 + kg * 8);
            acc[mf] = __builtin_amdgcn_mfma_f32_16x16x32_bf16(a, b, acc[mf], 0, 0, 0);
        }
    }
    if (nd < N) {
        #pragma unroll
        for (int mf = 0; mf < 16; ++mf) {
            int o = mf * 16 + kg * 4;
            float b0 = 0.f, b1v = 0.f, b2v = 0.f, b3v = 0.f;
            if (o < 128) { f32x4 bb = *(const f32x4*)(b1 + o); b0 = bb[0]; b1v = bb[1]; b2v = bb[2]; b3v = bb[3]; }
            *(uint2*)(apre + (size_t)nd * 256 + o) =
                make_uint2(pk2(acc[mf][0] + b0, acc[mf][1] + b1v), pk2(acc[mf][2] + b2v, acc[mf][3] + b3v));
        }
    }
}

// ================= edge kernel: sorted edges, gather apre, 3 MFMA stages, segmented reduce =================
__global__ __launch_bounds__(256) void edge_mfma_kernel(
    const float* __restrict__ pos, const unsigned short* __restrict__ apre,
    const float* __restrict__ eattr, const int* __restrict__ ei, const int* __restrict__ perm,
    const unsigned short* __restrict__ wattr,
    const unsigned short* __restrict__ wt2, const float* __restrict__ b2,
    const unsigned short* __restrict__ cwt1, const float* __restrict__ cb1,
    const float* __restrict__ cw2,
    float* __restrict__ agg, float* __restrict__ pos_agg, int E)
{
    __shared__ __align__(16) char s_at[EB * LDA];   // [64][32e] attr+radial bf16
    __shared__ __align__(16) char s_m1[EB * LDM];   // m1 bf16; aliased by m after sync
    __shared__ float s_cd[EB][3];
    __shared__ float s_s[EB];
    __shared__ int s_row[EB], s_col[EB], s_eid[EB];

    const int tid = threadIdx.x;
    const int lane = tid & 63, wv = tid >> 6, lr = lane & 15, kg = lane >> 4;
    const int e0 = blockIdx.x * EB;

    if (tid < EB) {
        int i = e0 + tid;
        int eid = perm[min(i, E - 1)];
        int r = ei[eid], c = ei[E + eid];
        s_eid[tid] = eid; s_row[tid] = r; s_col[tid] = c;
        float dx = pos[r*3+0] - pos[c*3+0];
        float dy = pos[r*3+1] - pos[c*3+1];
        float dz = pos[r*3+2] - pos[c*3+2];
        s_cd[tid][0] = dx; s_cd[tid][1] = dy; s_cd[tid][2] = dz;
        float rad = dx*dx + dy*dy + dz*dz;
        char* rowp = s_at + tid * LDA;
        *(unsigned*)(rowp + 32) = (unsigned)f2bf(rad);   // elem16=radial, elem17=0
        *(unsigned*)(rowp + 36) = 0u;
        *(uint2*)(rowp + 40) = make_uint2(0u, 0u);
        *(uint2*)(rowp + 48) = make_uint2(0u, 0u);
        *(uint2*)(rowp + 56) = make_uint2(0u, 0u);
    }
    __syncthreads();
    {   // eattr -> elems 0..15
        int et = tid >> 2, q = tid & 3;
        float4 v = ld4(eattr + (size_t)s_eid[et] * 16 + q * 4);
        *(uint2*)(s_at + et * LDA + q * 8) = make_uint2(pk2(v.x, v.y), pk2(v.z, v.w));
    }
    __syncthreads();

    const int el = wv * 16 + lr;
    const int esw = (el & 7) << 4;
    const int row = s_row[el], col = s_col[el];

    // ---- GEMM1': attr/radial k-step + gathered apre + silu -> s_m1
    f32x4 acc[8];
    #pragma unroll
    for (int mf = 0; mf < 8; ++mf) acc[mf] = (f32x4){0.f, 0.f, 0.f, 0.f};
    uint2 rg[8], cg[8];
    {
        const unsigned short* rbase = apre + (size_t)row * 256 + kg * 4;
        const unsigned short* cbase = apre + (size_t)col * 256 + 128 + kg * 4;
        #pragma unroll
        for (int mf = 0; mf < 8; ++mf) {
            rg[mf] = *(const uint2*)(rbase + mf * 16);
            cg[mf] = *(const uint2*)(cbase + mf * 16);
        }
        s16x8 b = *(const s16x8*)(s_at + el * LDA + kg * 16);
        #pragma unroll
        for (int mf = 0; mf < 8; ++mf) {
            s16x8 a = *(const s16x8*)(wattr + (size_t)(mf * 16 + lr) * 32 + kg * 8);
            acc[mf] = __builtin_amdgcn_mfma_f32_16x16x32_bf16(a, b, acc[mf], 0, 0, 0);
        }
    }
    char* mrow = s_m1 + el * LDM;
    #pragma unroll
    for (int mf = 0; mf < 8; ++mf) {
        float v0 = silu_f(acc[mf][0] + bf2f(rg[mf].x & 0xffffu)  + bf2f(cg[mf].x & 0xffffu));
        float v1 = silu_f(acc[mf][1] + bf2f(rg[mf].x >> 16)      + bf2f(cg[mf].x >> 16));
        float v2 = silu_f(acc[mf][2] + bf2f(rg[mf].y & 0xffffu)  + bf2f(cg[mf].y & 0xffffu));
        float v3 = silu_f(acc[mf][3] + bf2f(rg[mf].y >> 16)      + bf2f(cg[mf].y >> 16));
        *(uint2*)(mrow + ((mf * 32 + kg * 8) ^ esw)) = make_uint2(pk2(v0, v1), pk2(v2, v3));
    }
    __syncthreads();

    // ---- GEMM2: m = silu(m1 @ W2 + b2) -> s_m1 (aliased)
    #pragma unroll
    for (int mf = 0; mf < 8; ++mf) acc[mf] = (f32x4){0.f, 0.f, 0.f, 0.f};
    for (int ks = 0; ks < 4; ++ks) {
        s16x8 b = *(const s16x8*)(mrow + ((ks * 64 + kg * 16) ^ esw));
        #pragma unroll
        for (int mf = 0; mf < 8; ++mf) {
            s16x8 a = *(const s16x8*)(wt2 + (size_t)(mf * 16 + lr) * 128 + ks * 32 + kg * 8);
            acc[mf] = __builtin_amdgcn_mfma_f32_16x16x32_bf16(a, b, acc[mf], 0, 0, 0);
        }
    }
    __syncthreads();   // all reads of m1 done before aliased write
    #pragma unroll
    for (int mf = 0; mf < 8; ++mf) {
        f32x4 bb = *(const f32x4*)(b2 + mf * 16 + kg * 4);
        float v0 = silu_f(acc[mf][0] + bb[0]);
        float v1 = silu_f(acc[mf][1] + bb[1]);
        float v2 = silu_f(acc[mf][2] + bb[2]);
        float v3 = silu_f(acc[mf][3] + bb[3]);
        *(uint2*)(mrow + ((mf * 32 + kg * 8) ^ esw)) = make_uint2(pk2(v0, v1), pk2(v2, v3));
    }
    __syncthreads();

    // ---- GEMM3: s = silu(m @ CW1 + cb1) @ cw2
    #pragma unroll
    for (int mf = 0; mf < 8; ++mf) acc[mf] = (f32x4){0.f, 0.f, 0.f, 0.f};
    for (int ks = 0; ks < 4; ++ks) {
        s16x8 b = *(const s16x8*)(mrow + ((ks * 64 + kg * 16) ^ esw));
        #pragma unroll
        for (int mf = 0; mf < 8; ++mf) {
            s16x8 a = *(const s16x8*)(cwt1 + (size_t)(mf * 16 + lr) * 128 + ks * 32 + kg * 8);
            acc[mf] = __builtin_amdgcn_mfma_f32_16x16x32_bf16(a, b, acc[mf], 0, 0, 0);
        }
    }
    {
        float part = 0.f;
        #pragma unroll
        for (int mf = 0; mf < 8; ++mf) {
            f32x4 bb = *(const f32x4*)(cb1 + mf * 16 + kg * 4);
            f32x4 cw = *(const f32x4*)(cw2 + mf * 16 + kg * 4);
            part += silu_f(acc[mf][0] + bb[0]) * cw[0];
            part += silu_f(acc[mf][1] + bb[1]) * cw[1];
            part += silu_f(acc[mf][2] + bb[2]) * cw[2];
            part += silu_f(acc[mf][3] + bb[3]) * cw[3];
        }
        part += __shfl_xor(part, 16, 64);
        part += __shfl_xor(part, 32, 64);
        if (lane < 16) s_s[wv * 16 + lane] = part;
    }
    __syncthreads();

    // ---- segmented reduce over sorted rows: few atomics per block
    if (tid < 131) {
        if (tid < 128) {
            const int f = tid;
            float a = 0.f;
            int cur = (e0 < E) ? s_row[0] : -1;
            for (int e = 0; e < EB; ++e) {
                int r = (e0 + e < E) ? s_row[e] : -1;
                if (r != cur) {
                    if (cur >= 0) atomicAdd(&agg[(size_t)cur * 128 + f], a);
                    a = 0.f; cur = r;
                }
                a += bf2f(*(const unsigned short*)(s_m1 + e * LDM + ((f * 2) ^ ((e & 7) << 4))));
            }
            if (cur >= 0) atomicAdd(&agg[(size_t)cur * 128 + f], a);
        } else {
            const int d = tid - 128;
            float a = 0.f;
            int cur = (e0 < E) ? s_row[0] : -1;
            for (int e = 0; e < EB; ++e) {
                int r = (e0 + e < E) ? s_row[e] : -1;
                if (r != cur) {
                    if (cur >= 0) atomicAdd(&pos_agg[(size_t)cur * 3 + d], a);
                    a = 0.f; cur = r;
                }
                a += s_cd[e][d] * s_s[e];
            }
            if (cur >= 0) atomicAdd(&pos_agg[(size_t)cur * 3 + d], a);
        }
    }
}

// ================= pos += pos_agg / max(deg,1) =================
__global__ void posupd_kernel(float* __restrict__ pos, const float* __restrict__ pos_agg,
                              const int* __restrict__ rp, int N) {
    int i = blockIdx.x * 256 + threadIdx.x;
    if (i < N * 3) {
        int n = i / 3;
        float deg = (float)(rp[n + 1] - rp[n]);
        pos[i] += pos_agg[i] / fmaxf(deg, 1.0f);
    }
}

// ================= node model via MFMA: h += silu([h,agg]@W1+b1)@W2+b2 =================
__global__ __launch_bounds__(256) void node_mfma_kernel(
    float* __restrict__ h, const float* __restrict__ agg,
    const unsigned short* __restrict__ nw1t, const float* __restrict__ nb1,
    const unsigned short* __restrict__ nw2t, const float* __restrict__ nb2, int N)
{
    __shared__ __align__(16) char s_x[64 * 512];   // [64][256e] bf16 concat, swizzled
    __shared__ __align__(16) char s_t[64 * 256];   // [64][128e] hidden
    const int tid = threadIdx.x;
    const int lane = tid & 63, wv = tid >> 6, lr = lane & 15, kg = lane >> 4;
    const int n0 = blockIdx.x * 64;
    {
        int node = tid >> 2, q = tid & 3;
        int nn = min(n0 + node, N - 1);
        int sw = (node & 7) << 4;
        #pragma unroll
        for (int it = 0; it < 8; ++it) {
            int c = q * 32 + it * 4;
            float4 v = ld4(h + (size_t)nn * HD + c);
            *(uint2*)(s_x + node * 512 + ((c * 2) ^ sw)) = make_uint2(pk2(v.x, v.y), pk2(v.z, v.w));
            float4 u = ld4(agg + (size_t)nn * HD + c);
            *(uint2*)(s_x + node * 512 + ((256 + c * 2) ^ sw)) = make_uint2(pk2(u.x, u.y), pk2(u.z, u.w));
        }
    }
    __syncthreads();
    const int el = wv * 16 + lr;
    const int esw = (el & 7) << 4;
    const int nd = n0 + el;
    f32x4 acc[8];
    #pragma unroll
    for (int mf = 0; mf < 8; ++mf) acc[mf] = (f32x4){0.f, 0.f, 0.f, 0.f};
    for (int ks = 0; ks < 8; ++ks) {
        s16x8 b = *(const s16x8*)(s_x + el * 512 + ((ks * 64 + kg * 16) ^ esw));
        #pragma unroll
        for (int mf = 0; mf < 8; ++mf) {
            s16x8 a = *(const s16x8*)(nw1t + (size_t)(mf * 16 + lr) * 256 + ks * 32 + kg * 8);
            acc[mf] = __builtin_amdgcn_mfma_f32_16x16x32_bf16(a, b, acc[mf], 0, 0, 0);
        }
    }
    char* trow = s_t + el * 256;
    #pragma unroll
    for (int mf = 0; mf < 8; ++mf) {
        f32x4 bb = *(const f32x4*)(nb1 + mf * 16 + kg * 4);
        float v0 = silu_f(acc[mf][0] + bb[0]);
        float v1 = silu_f(acc[mf][1] + bb[1]);
        float v2 = silu_f(acc[mf][2] + bb[2]);
        float v3 = silu_f(acc[mf][3] + bb[3]);
        *(uint2*)(trow + ((mf * 32 + kg * 8) ^ esw)) = make_uint2(pk2(v0, v1), pk2(v2, v3));
    }
    __syncthreads();
    #pragma unroll
    for (int mf = 0; mf < 8; ++mf) acc[mf] = (f32x4){0.f, 0.f, 0.f, 0.f};
    for (int ks = 0; ks < 4; ++ks) {
        s16x8 b = *(const s16x8*)(trow + ((ks * 64 + kg * 16) ^ esw));
        #pragma unroll
        for (int mf = 0; mf < 8; ++mf) {
            s16x8 a = *(const s16x8*)(nw2t + (size_t)(mf * 16 + lr) * 128 + ks * 32 + kg * 8);
            acc[mf] = __builtin_amdgcn_mfma_f32_16x16x32_bf16(a, b, acc[mf], 0, 0, 0);
        }
    }
    if (nd < N) {
        #pragma unroll
        for (int mf = 0; mf < 8; ++mf) {
            f32x4 bb = *(const f32x4*)(nb2 + mf * 16 + kg * 4);
            float* hp = h + (size_t)nd * HD + mf * 16 + kg * 4;
            f32x4 hv = *(const f32x4*)hp;
            hv[0] += acc[mf][0] + bb[0];
            hv[1] += acc[mf][1] + bb[1];
            hv[2] += acc[mf][2] + bb[2];
            hv[3] += acc[mf][3] + bb[3];
            *(f32x4*)hp = hv;
        }
    }
}

// ================= g_enc init =================
__global__ void ginit_kernel(unsigned* __restrict__ g_enc, int n) {
    int i = blockIdx.x * 256 + threadIdx.x;
    if (i < n) g_enc[i] = 0x007FFFFFu;
}

// ================= h @ emb_out + b, segment_max =================
__global__ __launch_bounds__(128) void embout_segmax_kernel(
    const float* __restrict__ h, const float* __restrict__ w, const float* __restrict__ b,
    const int* __restrict__ batch, unsigned* __restrict__ g_enc, int N)
{
    __shared__ __align__(16) float s_x[HD][12];
    const int tid = threadIdx.x;
    const int n0 = blockIdx.x * NPB;
    #pragma unroll
    for (int n = 0; n < NPB; ++n) {
        int nn = min(n0 + n, N - 1);
        s_x[tid][n] = h[(size_t)nn * HD + tid];
    }
    __syncthreads();
    float acc[NPB];
    {
        float bias = b[tid];
        #pragma unroll
        for (int n = 0; n < NPB; ++n) acc[n] = bias;
    }
    for (int k = 0; k < HD; ++k) {
        float wv = w[(size_t)k * HD + tid];
        float4 x0 = ld4(&s_x[k][0]);
        float4 x1 = ld4(&s_x[k][4]);
        acc[0] += x0.x * wv; acc[1] += x0.y * wv; acc[2] += x0.z * wv; acc[3] += x0.w * wv;
        acc[4] += x1.x * wv; acc[5] += x1.y * wv; acc[6] += x1.z * wv; acc[7] += x1.w * wv;
    }
    #pragma unroll
    for (int n = 0; n < NPB; ++n) {
        if (n0 + n < N) {
            unsigned u = __float_as_uint(acc[n]);
            u = (u & 0x80000000u) ? ~u : (u | 0x80000000u);
            atomicMax(&g_enc[(size_t)batch[n0 + n] * HD + tid], u);
        }
    }
}

// ================= decode + 2 ResBlocks =================
__global__ __launch_bounds__(128) void resblock_kernel(
    const unsigned* __restrict__ g_enc,
    const float* __restrict__ rw1, const float* __restrict__ rb1,
    const float* __restrict__ rw2, const float* __restrict__ rb2,
    float* __restrict__ g)
{
    __shared__ float s_g[HD];
    __shared__ float s_t[HD];
    const int b = blockIdx.x, j = threadIdx.x;
    unsigned u = g_enc[(size_t)b * HD + j];
    float v = (u & 0x80000000u) ? __uint_as_float(u & 0x7FFFFFFFu) : __uint_as_float(~u);
    s_g[j] = v;
    __syncthreads();
    for (int r = 0; r < 2; ++r) {
        float a1 = rb1[r * HD + j];
        for (int k = 0; k < HD; ++k) a1 += s_g[k] * rw1[(size_t)r * HD * HD + (size_t)k * HD + j];
        s_t[j] = silu_f(a1);
        __syncthreads();
        float a2 = rb2[r * HD + j];
        for (int k = 0; k < HD; ++k) a2 += s_t[k] * rw2[(size_t)r * HD * HD + (size_t)k * HD + j];
        __syncthreads();
        s_g[j] += a2;
        __syncthreads();
    }
    g[(size_t)b * HD + j] = s_g[j];
}

// ================= head =================
__global__ __launch_bounds__(256) void head_kernel(
    const float* __restrict__ g, const float* __restrict__ hw, const float* __restrict__ hb,
    float* __restrict__ out)
{
    __shared__ float s_g[HD];
    const int b = blockIdx.y;
    const int p = blockIdx.x * 256 + threadIdx.x;
    if (threadIdx.x < HD) s_g[threadIdx.x] = g[(size_t)b * HD + threadIdx.x];
    __syncthreads();
    if (p >= PROP) return;
    float acc = hb[p];
    for (int k = 0; k < HD; ++k) acc += s_g[k] * hw[(size_t)k * PROP + p];
    out[(size_t)b * PROP + p] = acc;
}

extern "C" void kernel_launch(void* const* d_in, const int* in_sizes, int n_in,
                              void* d_out, int out_size, void* d_ws, size_t ws_size,
                              hipStream_t stream)
{
    const float* x        = (const float*)d_in[0];
    const float* pos_in   = (const float*)d_in[1];
    const float* eattr    = (const float*)d_in[2];
    const int*   ei       = (const int*)d_in[3];
    const int*   batch    = (const int*)d_in[4];
    const float* emb_in_w = (const float*)d_in[5];
    const float* emb_in_b = (const float*)d_in[6];
    const float* emb_out_w= (const float*)d_in[7];
    const float* emb_out_b= (const float*)d_in[8];
    const float* ew1 = (const float*)d_in[9];
    const float* eb1 = (const float*)d_in[10];
    const float* ew2 = (const float*)d_in[11];
    const float* eb2 = (const float*)d_in[12];
    const float* nw1 = (const float*)d_in[13];
    const float* nb1 = (const float*)d_in[14];
    const float* nw2 = (const float*)d_in[15];
    const float* nb2 = (const float*)d_in[16];
    const float* cw1 = (const float*)d_in[17];
    const float* cb1 = (const float*)d_in[18];
    const float* cw2 = (const float*)d_in[19];
    const float* rw1 = (const float*)d_in[20];
    const float* rb1 = (const float*)d_in[21];
    const float* rw2 = (const float*)d_in[22];
    const float* rb2 = (const float*)d_in[23];
    const float* hw  = (const float*)d_in[24];
    const float* hb  = (const float*)d_in[25];
    float* out = (float*)d_out;
    (void)ws_size;

    const int N = in_sizes[0] / 64;     // 20000
    const int E = in_sizes[2] / 16;     // 160000
    const int B = out_size / PROP;      // 1024

    // ---- workspace carve-up (f32, then bf16, then int) ----
    float* wsf = (float*)d_ws;
    float* pos_cur = wsf;   wsf += (size_t)N * 3;
    float* pos_agg = wsf;   wsf += (size_t)N * 3;
    float* h       = wsf;   wsf += (size_t)N * HD;
    float* agg     = wsf;   wsf += (size_t)N * HD;
    float* g       = wsf;   wsf += (size_t)B * HD;
    wsf += (4 - (((size_t)(wsf - (float*)d_ws)) & 3)) & 3;   // 16B align
    unsigned short* apre  = (unsigned short*)wsf;
    unsigned short* w1nc  = apre  + (size_t)N * 256;
    unsigned short* wattr = w1nc  + (size_t)4 * 256 * 128;
    unsigned short* wt2   = wattr + (size_t)4 * 128 * 32;
    unsigned short* cwt1  = wt2   + (size_t)4 * 128 * 128;
    unsigned short* nw1t  = cwt1  + (size_t)4 * 128 * 128;
    unsigned short* nw2t  = nw1t  + (size_t)4 * 128 * 256;
    int* ip   = (int*)(nw2t + (size_t)4 * 128 * 128);
    unsigned* g_enc = (unsigned*)ip;  ip += (size_t)B * HD;
    int* cnt_i = ip;  ip += N;
    int* rp    = ip;  ip += N + 1;
    int* wp    = ip;  ip += N;
    int* perm  = ip;  ip += E;

    // ---- weight prep ----
    prep_w1nc<<<(4 * 256 * 128 + 255) / 256, 256, 0, stream>>>(ew1, w1nc);
    prep_wattr<<<(4 * 128 * 32 + 255) / 256, 256, 0, stream>>>(ew1, wattr);
    prep_t<<<(4 * 128 * 128 + 255) / 256, 256, 0, stream>>>(ew2, wt2, 128);
    prep_t<<<(4 * 128 * 128 + 255) / 256, 256, 0, stream>>>(cw1, cwt1, 128);
    prep_t<<<(4 * 128 * 256 + 255) / 256, 256, 0, stream>>>(nw1, nw1t, 256);
    prep_t<<<(4 * 128 * 128 + 255) / 256, 256, 0, stream>>>(nw2, nw2t, 128);

    // ---- CSR build ----
    hipMemsetAsync(cnt_i, 0, (size_t)N * sizeof(int), stream);
    counti_kernel<<<(E + 255) / 256, 256, 0, stream>>>(ei, cnt_i, E);
    scan_kernel<<<1, 1024, 0, stream>>>(cnt_i, rp, wp, N);
    scatter_kernel<<<(E + 255) / 256, 256, 0, stream>>>(ei, wp, perm, E);

    hipMemcpyAsync(pos_cur, pos_in, (size_t)N * 3 * sizeof(float),
                   hipMemcpyDeviceToDevice, stream);
    emb_kernel<<<(N + NPB - 1) / NPB, 128, 0, stream>>>(x, emb_in_w, emb_in_b, h, N);

    const int nblk = (N + 63) / 64;
    for (int l = 0; l < 4; ++l) {
        node_pre_kernel<<<nblk, 256, 0, stream>>>(
            h, w1nc + (size_t)l * 256 * 128, eb1 + (size_t)l * HD, apre, N);
        hipMemsetAsync(agg, 0, (size_t)N * HD * sizeof(float), stream);
        hipMemsetAsync(pos_agg, 0, (size_t)N * 3 * sizeof(float), stream);
        edge_mfma_kernel<<<(E + EB - 1) / EB, 256, 0, stream>>>(
            pos_cur, apre, eattr, ei, perm,
            wattr + (size_t)l * 128 * 32,
            wt2  + (size_t)l * 128 * 128, eb2 + (size_t)l * HD,
            cwt1 + (size_t)l * 128 * 128, cb1 + (size_t)l * HD,
            cw2 + (size_t)l * HD,
            agg, pos_agg, E);
        posupd_kernel<<<(N * 3 + 255) / 256, 256, 0, stream>>>(pos_cur, pos_agg, rp, N);
        node_mfma_kernel<<<nblk, 256, 0, stream>>>(
            h, agg,
            nw1t + (size_t)l * 128 * 256, nb1 + (size_t)l * HD,
            nw2t + (size_t)l * 128 * 128, nb2 + (size_t)l * HD, N);
    }

    ginit_kernel<<<(B * HD + 255) / 256, 256, 0, stream>>>(g_enc, B * HD);
    embout_segmax_kernel<<<(N + NPB - 1) / NPB, 128, 0, stream>>>(
        h, emb_out_w, emb_out_b, batch, g_enc, N);
    resblock_kernel<<<B, 128, 0, stream>>>(g_enc, rw1, rb1, rw2, rb2, g);
    head_kernel<<<dim3((PROP + 255) / 256, B), 256, 0, stream>>>(g, hw, hb, out);
}

// Round 4
// 888.489 us; speedup vs baseline: 2.4167x; 1.0010x over previous
//
#include <hip/hip_runtime.h>

#define HD 128
#define PROP 1000
#define EB   64           // edges per block
#define LDA  80           // attr k-slice LDS row stride (bytes)
#define LDM  256          // m1/m LDS row stride (bytes)
#define NPB  8            // nodes per block (VALU node-wise kernels)

typedef float f32x4 __attribute__((ext_vector_type(4)));
typedef short s16x8 __attribute__((ext_vector_type(8)));

__device__ __forceinline__ float silu_f(float v) { return v / (1.0f + __expf(-v)); }
__device__ __forceinline__ unsigned short f2bf(float f) {
    union { float f; unsigned u; } v; v.f = f;
    unsigned r = v.u + 0x7FFFu + ((v.u >> 16) & 1u);   // RNE
    return (unsigned short)(r >> 16);
}
__device__ __forceinline__ unsigned pk2(float a, float b) {
    return (unsigned)f2bf(a) | ((unsigned)f2bf(b) << 16);
}
__device__ __forceinline__ float bf2f(unsigned s) { return __uint_as_float(s << 16); }
__device__ __forceinline__ float4 ld4(const float* p) { return *(const float4*)p; }

// ================= CSR build =================
__global__ void counti_kernel(const int* __restrict__ ei, int* __restrict__ cnt, int E) {
    int e = blockIdx.x * 256 + threadIdx.x;
    if (e < E) atomicAdd(&cnt[ei[e]], 1);
}

__global__ __launch_bounds__(1024) void scan_kernel(
    const int* __restrict__ cnt, int* __restrict__ rp, int* __restrict__ wp, int N)
{
    __shared__ int s[1024];
    __shared__ int carry;
    const int tid = threadIdx.x;
    if (tid == 0) carry = 0;
    __syncthreads();
    for (int base = 0; base < N; base += 1024) {
        int v = (base + tid < N) ? cnt[base + tid] : 0;
        s[tid] = v;
        __syncthreads();
        for (int off = 1; off < 1024; off <<= 1) {
            int t = (tid >= off) ? s[tid - off] : 0;
            __syncthreads();
            s[tid] += t;
            __syncthreads();
        }
        int excl = carry + s[tid] - v;
        if (base + tid < N) { rp[base + tid] = excl; wp[base + tid] = excl; }
        __syncthreads();
        if (tid == 0) carry += s[1023];
        __syncthreads();
    }
    if (tid == 0) rp[N] = carry;
}

__global__ void scatter_kernel(const int* __restrict__ ei, int* __restrict__ wp,
                               int* __restrict__ perm, int E) {
    int e = blockIdx.x * 256 + threadIdx.x;
    if (e < E) {
        int p = atomicAdd(&wp[ei[e]], 1);
        perm[p] = e;
    }
}

// ================= weight prep =================
// w1nc_t[l][o2<256][k<128]: o2<128 -> ew1 rows 0..127 ; o2>=128 -> rows 128..255
__global__ void prep_w1nc(const float* __restrict__ ew1, unsigned short* __restrict__ dst) {
    int idx = blockIdx.x * 256 + threadIdx.x;
    if (idx >= 4 * 256 * 128) return;
    int k = idx & 127, o2 = (idx >> 7) & 255, l = idx >> 15;
    dst[idx] = f2bf(ew1[((size_t)l * 273 + k + ((o2 >> 7) << 7)) * 128 + (o2 & 127)]);
}
// wattr_t[l][o][k<32]: k<16 -> eattr rows (257+k); k==16 -> radial row 256; else 0
__global__ void prep_wattr(const float* __restrict__ ew1, unsigned short* __restrict__ dst) {
    int idx = blockIdx.x * 256 + threadIdx.x;
    if (idx >= 4 * 128 * 32) return;
    int k = idx & 31, o = (idx >> 5) & 127, l = idx >> 12;
    int ksrc = (k < 16) ? (257 + k) : (k == 16 ? 256 : -1);
    float v = (ksrc >= 0) ? ew1[((size_t)l * 273 + ksrc) * 128 + o] : 0.0f;
    dst[idx] = f2bf(v);
}
// generic transpose: src [4][K][128] -> dst [4][128][K]
__global__ void prep_t(const float* __restrict__ src, unsigned short* __restrict__ dst, int K) {
    int idx = blockIdx.x * 256 + threadIdx.x;
    if (idx >= 4 * 128 * K) return;
    int k = idx % K, o = (idx / K) & 127, l = idx / (K * 128);
    dst[idx] = f2bf(src[((size_t)l * K + k) * 128 + o]);
}

// ================= h = x @ W(64x128) + b =================
__global__ __launch_bounds__(128) void emb_kernel(
    const float* __restrict__ x, const float* __restrict__ w, const float* __restrict__ b,
    float* __restrict__ h, int N)
{
    __shared__ __align__(16) float s_x[64][12];
    const int tid = threadIdx.x;
    const int n0 = blockIdx.x * NPB;
    if (tid < 64) {
        #pragma unroll
        for (int n = 0; n < NPB; ++n) {
            int nn = min(n0 + n, N - 1);
            s_x[tid][n] = x[(size_t)nn * 64 + tid];
        }
    }
    __syncthreads();
    float bias = b[tid];
    float acc[NPB];
    #pragma unroll
    for (int n = 0; n < NPB; ++n) acc[n] = bias;
    for (int k = 0; k < 64; ++k) {
        float wv = w[(size_t)k * HD + tid];
        float4 x0 = ld4(&s_x[k][0]);
        float4 x1 = ld4(&s_x[k][4]);
        acc[0] += x0.x * wv; acc[1] += x0.y * wv; acc[2] += x0.z * wv; acc[3] += x0.w * wv;
        acc[4] += x1.x * wv; acc[5] += x1.y * wv; acc[6] += x1.z * wv; acc[7] += x1.w * wv;
    }
    #pragma unroll
    for (int n = 0; n < NPB; ++n)
        if (n0 + n < N) h[(size_t)(n0 + n) * HD + tid] = acc[n];
}

// ================= node_pre: apre[n][0:128]=h@W1row+b1 ; [128:256]=h@W1col (bf16) =================
__global__ __launch_bounds__(256) void node_pre_kernel(
    const float* __restrict__ h, const unsigned short* __restrict__ w1nc,
    const float* __restrict__ b1, unsigned short* __restrict__ apre, int N)
{
    __shared__ __align__(16) char s_h[64 * 256];   // bf16 [64 nodes][128 feats], swizzled
    const int tid = threadIdx.x;
    const int lane = tid & 63, wv = tid >> 6, lr = lane & 15, kg = lane >> 4;
    const int n0 = blockIdx.x * 64;
    {
        int node = tid >> 2, q = tid & 3;
        int nn = min(n0 + node, N - 1);
        int sw = (node & 7) << 4;
        #pragma unroll
        for (int it = 0; it < 8; ++it) {
            int c = q * 32 + it * 4;
            float4 v = ld4(h + (size_t)nn * HD + c);
            *(uint2*)(s_h + node * 256 + ((c * 2) ^ sw)) = make_uint2(pk2(v.x, v.y), pk2(v.z, v.w));
        }
    }
    __syncthreads();
    const int el = wv * 16 + lr;
    const int esw = (el & 7) << 4;
    const int nd = n0 + el;
    f32x4 acc[16];
    #pragma unroll
    for (int mf = 0; mf < 16; ++mf) acc[mf] = (f32x4){0.f, 0.f, 0.f, 0.f};
    const char* brow = s_h + el * 256;
    for (int ks = 0; ks < 4; ++ks) {
        s16x8 b = *(const s16x8*)(brow + ((ks * 64 + kg * 16) ^ esw));
        #pragma unroll
        for (int mf = 0; mf < 16; ++mf) {
            s16x8 a = *(const s16x8*)(w1nc + (size_t)(mf * 16 + lr) * 128 + ks * 32 + kg * 8);
            acc[mf] = __builtin_amdgcn_mfma_f32_16x16x32_bf16(a, b, acc[mf], 0, 0, 0);
        }
    }
    if (nd < N) {
        #pragma unroll
        for (int mf = 0; mf < 16; ++mf) {
            int o = mf * 16 + kg * 4;
            float b0 = 0.f, b1v = 0.f, b2v = 0.f, b3v = 0.f;
            if (o < 128) { f32x4 bb = *(const f32x4*)(b1 + o); b0 = bb[0]; b1v = bb[1]; b2v = bb[2]; b3v = bb[3]; }
            *(uint2*)(apre + (size_t)nd * 256 + o) =
                make_uint2(pk2(acc[mf][0] + b0, acc[mf][1] + b1v), pk2(acc[mf][2] + b2v, acc[mf][3] + b3v));
        }
    }
}

// ================= edge kernel: sorted edges, gather apre, 3 MFMA stages, segmented reduce =================
__global__ __launch_bounds__(256) void edge_mfma_kernel(
    const float* __restrict__ pos, const unsigned short* __restrict__ apre,
    const float* __restrict__ eattr, const int* __restrict__ ei, const int* __restrict__ perm,
    const unsigned short* __restrict__ wattr,
    const unsigned short* __restrict__ wt2, const float* __restrict__ b2,
    const unsigned short* __restrict__ cwt1, const float* __restrict__ cb1,
    const float* __restrict__ cw2,
    float* __restrict__ agg, float* __restrict__ pos_agg, int E)
{
    __shared__ __align__(16) char s_at[EB * LDA];   // [64][32e] attr+radial bf16
    __shared__ __align__(16) char s_m1[EB * LDM];   // m1 bf16; aliased by m after sync
    __shared__ float s_cd[EB][3];
    __shared__ float s_s[EB];
    __shared__ int s_row[EB], s_col[EB], s_eid[EB];

    const int tid = threadIdx.x;
    const int lane = tid & 63, wv = tid >> 6, lr = lane & 15, kg = lane >> 4;
    const int e0 = blockIdx.x * EB;

    if (tid < EB) {
        int i = e0 + tid;
        int eid = perm[min(i, E - 1)];
        int r = ei[eid], c = ei[E + eid];
        s_eid[tid] = eid; s_row[tid] = r; s_col[tid] = c;
        float dx = pos[r*3+0] - pos[c*3+0];
        float dy = pos[r*3+1] - pos[c*3+1];
        float dz = pos[r*3+2] - pos[c*3+2];
        s_cd[tid][0] = dx; s_cd[tid][1] = dy; s_cd[tid][2] = dz;
        float rad = dx*dx + dy*dy + dz*dz;
        char* rowp = s_at + tid * LDA;
        *(unsigned*)(rowp + 32) = (unsigned)f2bf(rad);   // elem16=radial, elem17=0
        *(unsigned*)(rowp + 36) = 0u;
        *(uint2*)(rowp + 40) = make_uint2(0u, 0u);
        *(uint2*)(rowp + 48) = make_uint2(0u, 0u);
        *(uint2*)(rowp + 56) = make_uint2(0u, 0u);
    }
    __syncthreads();
    {   // eattr -> elems 0..15
        int et = tid >> 2, q = tid & 3;
        float4 v = ld4(eattr + (size_t)s_eid[et] * 16 + q * 4);
        *(uint2*)(s_at + et * LDA + q * 8) = make_uint2(pk2(v.x, v.y), pk2(v.z, v.w));
    }
    __syncthreads();

    const int el = wv * 16 + lr;
    const int esw = (el & 7) << 4;
    const int row = s_row[el], col = s_col[el];

    // ---- GEMM1': attr/radial k-step + gathered apre + silu -> s_m1
    f32x4 acc[8];
    #pragma unroll
    for (int mf = 0; mf < 8; ++mf) acc[mf] = (f32x4){0.f, 0.f, 0.f, 0.f};
    uint2 rg[8], cg[8];
    {
        const unsigned short* rbase = apre + (size_t)row * 256 + kg * 4;
        const unsigned short* cbase = apre + (size_t)col * 256 + 128 + kg * 4;
        #pragma unroll
        for (int mf = 0; mf < 8; ++mf) {
            rg[mf] = *(const uint2*)(rbase + mf * 16);
            cg[mf] = *(const uint2*)(cbase + mf * 16);
        }
        s16x8 b = *(const s16x8*)(s_at + el * LDA + kg * 16);
        #pragma unroll
        for (int mf = 0; mf < 8; ++mf) {
            s16x8 a = *(const s16x8*)(wattr + (size_t)(mf * 16 + lr) * 32 + kg * 8);
            acc[mf] = __builtin_amdgcn_mfma_f32_16x16x32_bf16(a, b, acc[mf], 0, 0, 0);
        }
    }
    char* mrow = s_m1 + el * LDM;
    #pragma unroll
    for (int mf = 0; mf < 8; ++mf) {
        float v0 = silu_f(acc[mf][0] + bf2f(rg[mf].x & 0xffffu)  + bf2f(cg[mf].x & 0xffffu));
        float v1 = silu_f(acc[mf][1] + bf2f(rg[mf].x >> 16)      + bf2f(cg[mf].x >> 16));
        float v2 = silu_f(acc[mf][2] + bf2f(rg[mf].y & 0xffffu)  + bf2f(cg[mf].y & 0xffffu));
        float v3 = silu_f(acc[mf][3] + bf2f(rg[mf].y >> 16)      + bf2f(cg[mf].y >> 16));
        *(uint2*)(mrow + ((mf * 32 + kg * 8) ^ esw)) = make_uint2(pk2(v0, v1), pk2(v2, v3));
    }
    __syncthreads();

    // ---- GEMM2: m = silu(m1 @ W2 + b2) -> s_m1 (aliased)
    #pragma unroll
    for (int mf = 0; mf < 8; ++mf) acc[mf] = (f32x4){0.f, 0.f, 0.f, 0.f};
    for (int ks = 0; ks < 4; ++ks) {
        s16x8 b = *(const s16x8*)(mrow + ((ks * 64 + kg * 16) ^ esw));
        #pragma unroll
        for (int mf = 0; mf < 8; ++mf) {
            s16x8 a = *(const s16x8*)(wt2 + (size_t)(mf * 16 + lr) * 128 + ks * 32 + kg * 8);
            acc[mf] = __builtin_amdgcn_mfma_f32_16x16x32_bf16(a, b, acc[mf], 0, 0, 0);
        }
    }
    __syncthreads();   // all reads of m1 done before aliased write
    #pragma unroll
    for (int mf = 0; mf < 8; ++mf) {
        f32x4 bb = *(const f32x4*)(b2 + mf * 16 + kg * 4);
        float v0 = silu_f(acc[mf][0] + bb[0]);
        float v1 = silu_f(acc[mf][1] + bb[1]);
        float v2 = silu_f(acc[mf][2] + bb[2]);
        float v3 = silu_f(acc[mf][3] + bb[3]);
        *(uint2*)(mrow + ((mf * 32 + kg * 8) ^ esw)) = make_uint2(pk2(v0, v1), pk2(v2, v3));
    }
    __syncthreads();

    // ---- GEMM3: s = silu(m @ CW1 + cb1) @ cw2
    #pragma unroll
    for (int mf = 0; mf < 8; ++mf) acc[mf] = (f32x4){0.f, 0.f, 0.f, 0.f};
    for (int ks = 0; ks < 4; ++ks) {
        s16x8 b = *(const s16x8*)(mrow + ((ks * 64 + kg * 16) ^ esw));
        #pragma unroll
        for (int mf = 0; mf < 8; ++mf) {
            s16x8 a = *(const s16x8*)(cwt1 + (size_t)(mf * 16 + lr) * 128 + ks * 32 + kg * 8);
            acc[mf] = __builtin_amdgcn_mfma_f32_16x16x32_bf16(a, b, acc[mf], 0, 0, 0);
        }
    }
    {
        float part = 0.f;
        #pragma unroll
        for (int mf = 0; mf < 8; ++mf) {
            f32x4 bb = *(const f32x4*)(cb1 + mf * 16 + kg * 4);
            f32x4 cw = *(const f32x4*)(cw2 + mf * 16 + kg * 4);
            part += silu_f(acc[mf][0] + bb[0]) * cw[0];
            part += silu_f(acc[mf][1] + bb[1]) * cw[1];
            part += silu_f(acc[mf][2] + bb[2]) * cw[2];
            part += silu_f(acc[mf][3] + bb[3]) * cw[3];
        }
        part += __shfl_xor(part, 16, 64);
        part += __shfl_xor(part, 32, 64);
        if (lane < 16) s_s[wv * 16 + lane] = part;
    }
    __syncthreads();

    // ---- segmented reduce over sorted rows: few atomics per block
    if (tid < 131) {
        if (tid < 128) {
            const int f = tid;
            float a = 0.f;
            int cur = (e0 < E) ? s_row[0] : -1;
            for (int e = 0; e < EB; ++e) {
                int r = (e0 + e < E) ? s_row[e] : -1;
                if (r != cur) {
                    if (cur >= 0) atomicAdd(&agg[(size_t)cur * 128 + f], a);
                    a = 0.f; cur = r;
                }
                a += bf2f(*(const unsigned short*)(s_m1 + e * LDM + ((f * 2) ^ ((e & 7) << 4))));
            }
            if (cur >= 0) atomicAdd(&agg[(size_t)cur * 128 + f], a);
        } else {
            const int d = tid - 128;
            float a = 0.f;
            int cur = (e0 < E) ? s_row[0] : -1;
            for (int e = 0; e < EB; ++e) {
                int r = (e0 + e < E) ? s_row[e] : -1;
                if (r != cur) {
                    if (cur >= 0) atomicAdd(&pos_agg[(size_t)cur * 3 + d], a);
                    a = 0.f; cur = r;
                }
                a += s_cd[e][d] * s_s[e];
            }
            if (cur >= 0) atomicAdd(&pos_agg[(size_t)cur * 3 + d], a);
        }
    }
}

// ================= pos += pos_agg / max(deg,1) =================
__global__ void posupd_kernel(float* __restrict__ pos, const float* __restrict__ pos_agg,
                              const int* __restrict__ rp, int N) {
    int i = blockIdx.x * 256 + threadIdx.x;
    if (i < N * 3) {
        int n = i / 3;
        float deg = (float)(rp[n + 1] - rp[n]);
        pos[i] += pos_agg[i] / fmaxf(deg, 1.0f);
    }
}

// ================= node model via MFMA: h += silu([h,agg]@W1+b1)@W2+b2 =================
__global__ __launch_bounds__(256) void node_mfma_kernel(
    float* __restrict__ h, const float* __restrict__ agg,
    const unsigned short* __restrict__ nw1t, const float* __restrict__ nb1,
    const unsigned short* __restrict__ nw2t, const float* __restrict__ nb2, int N)
{
    __shared__ __align__(16) char s_x[64 * 512];   // [64][256e] bf16 concat, swizzled
    __shared__ __align__(16) char s_t[64 * 256];   // [64][128e] hidden
    const int tid = threadIdx.x;
    const int lane = tid & 63, wv = tid >> 6, lr = lane & 15, kg = lane >> 4;
    const int n0 = blockIdx.x * 64;
    {
        int node = tid >> 2, q = tid & 3;
        int nn = min(n0 + node, N - 1);
        int sw = (node & 7) << 4;
        #pragma unroll
        for (int it = 0; it < 8; ++it) {
            int c = q * 32 + it * 4;
            float4 v = ld4(h + (size_t)nn * HD + c);
            *(uint2*)(s_x + node * 512 + ((c * 2) ^ sw)) = make_uint2(pk2(v.x, v.y), pk2(v.z, v.w));
            float4 u = ld4(agg + (size_t)nn * HD + c);
            *(uint2*)(s_x + node * 512 + ((256 + c * 2) ^ sw)) = make_uint2(pk2(u.x, u.y), pk2(u.z, u.w));
        }
    }
    __syncthreads();
    const int el = wv * 16 + lr;
    const int esw = (el & 7) << 4;
    const int nd = n0 + el;
    f32x4 acc[8];
    #pragma unroll
    for (int mf = 0; mf < 8; ++mf) acc[mf] = (f32x4){0.f, 0.f, 0.f, 0.f};
    for (int ks = 0; ks < 8; ++ks) {
        s16x8 b = *(const s16x8*)(s_x + el * 512 + ((ks * 64 + kg * 16) ^ esw));
        #pragma unroll
        for (int mf = 0; mf < 8; ++mf) {
            s16x8 a = *(const s16x8*)(nw1t + (size_t)(mf * 16 + lr) * 256 + ks * 32 + kg * 8);
            acc[mf] = __builtin_amdgcn_mfma_f32_16x16x32_bf16(a, b, acc[mf], 0, 0, 0);
        }
    }
    char* trow = s_t + el * 256;
    #pragma unroll
    for (int mf = 0; mf < 8; ++mf) {
        f32x4 bb = *(const f32x4*)(nb1 + mf * 16 + kg * 4);
        float v0 = silu_f(acc[mf][0] + bb[0]);
        float v1 = silu_f(acc[mf][1] + bb[1]);
        float v2 = silu_f(acc[mf][2] + bb[2]);
        float v3 = silu_f(acc[mf][3] + bb[3]);
        *(uint2*)(trow + ((mf * 32 + kg * 8) ^ esw)) = make_uint2(pk2(v0, v1), pk2(v2, v3));
    }
    __syncthreads();
    #pragma unroll
    for (int mf = 0; mf < 8; ++mf) acc[mf] = (f32x4){0.f, 0.f, 0.f, 0.f};
    for (int ks = 0; ks < 4; ++ks) {
        s16x8 b = *(const s16x8*)(trow + ((ks * 64 + kg * 16) ^ esw));
        #pragma unroll
        for (int mf = 0; mf < 8; ++mf) {
            s16x8 a = *(const s16x8*)(nw2t + (size_t)(mf * 16 + lr) * 128 + ks * 32 + kg * 8);
            acc[mf] = __builtin_amdgcn_mfma_f32_16x16x32_bf16(a, b, acc[mf], 0, 0, 0);
        }
    }
    if (nd < N) {
        #pragma unroll
        for (int mf = 0; mf < 8; ++mf) {
            f32x4 bb = *(const f32x4*)(nb2 + mf * 16 + kg * 4);
            float* hp = h + (size_t)nd * HD + mf * 16 + kg * 4;
            f32x4 hv = *(const f32x4*)hp;
            hv[0] += acc[mf][0] + bb[0];
            hv[1] += acc[mf][1] + bb[1];
            hv[2] += acc[mf][2] + bb[2];
            hv[3] += acc[mf][3] + bb[3];
            *(f32x4*)hp = hv;
        }
    }
}

// ================= g_enc init =================
__global__ void ginit_kernel(unsigned* __restrict__ g_enc, int n) {
    int i = blockIdx.x * 256 + threadIdx.x;
    if (i < n) g_enc[i] = 0x007FFFFFu;
}

// ================= h @ emb_out + b, segment_max =================
__global__ __launch_bounds__(128) void embout_segmax_kernel(
    const float* __restrict__ h, const float* __restrict__ w, const float* __restrict__ b,
    const int* __restrict__ batch, unsigned* __restrict__ g_enc, int N)
{
    __shared__ __align__(16) float s_x[HD][12];
    const int tid = threadIdx.x;
    const int n0 = blockIdx.x * NPB;
    #pragma unroll
    for (int n = 0; n < NPB; ++n) {
        int nn = min(n0 + n, N - 1);
        s_x[tid][n] = h[(size_t)nn * HD + tid];
    }
    __syncthreads();
    float acc[NPB];
    {
        float bias = b[tid];
        #pragma unroll
        for (int n = 0; n < NPB; ++n) acc[n] = bias;
    }
    for (int k = 0; k < HD; ++k) {
        float wv = w[(size_t)k * HD + tid];
        float4 x0 = ld4(&s_x[k][0]);
        float4 x1 = ld4(&s_x[k][4]);
        acc[0] += x0.x * wv; acc[1] += x0.y * wv; acc[2] += x0.z * wv; acc[3] += x0.w * wv;
        acc[4] += x1.x * wv; acc[5] += x1.y * wv; acc[6] += x1.z * wv; acc[7] += x1.w * wv;
    }
    #pragma unroll
    for (int n = 0; n < NPB; ++n) {
        if (n0 + n < N) {
            unsigned u = __float_as_uint(acc[n]);
            u = (u & 0x80000000u) ? ~u : (u | 0x80000000u);
            atomicMax(&g_enc[(size_t)batch[n0 + n] * HD + tid], u);
        }
    }
}

// ================= decode + 2 ResBlocks =================
__global__ __launch_bounds__(128) void resblock_kernel(
    const unsigned* __restrict__ g_enc,
    const float* __restrict__ rw1, const float* __restrict__ rb1,
    const float* __restrict__ rw2, const float* __restrict__ rb2,
    float* __restrict__ g)
{
    __shared__ float s_g[HD];
    __shared__ float s_t[HD];
    const int b = blockIdx.x, j = threadIdx.x;
    unsigned u = g_enc[(size_t)b * HD + j];
    float v = (u & 0x80000000u) ? __uint_as_float(u & 0x7FFFFFFFu) : __uint_as_float(~u);
    s_g[j] = v;
    __syncthreads();
    for (int r = 0; r < 2; ++r) {
        float a1 = rb1[r * HD + j];
        for (int k = 0; k < HD; ++k) a1 += s_g[k] * rw1[(size_t)r * HD * HD + (size_t)k * HD + j];
        s_t[j] = silu_f(a1);
        __syncthreads();
        float a2 = rb2[r * HD + j];
        for (int k = 0; k < HD; ++k) a2 += s_t[k] * rw2[(size_t)r * HD * HD + (size_t)k * HD + j];
        __syncthreads();
        s_g[j] += a2;
        __syncthreads();
    }
    g[(size_t)b * HD + j] = s_g[j];
}

// ================= head =================
__global__ __launch_bounds__(256) void head_kernel(
    const float* __restrict__ g, const float* __restrict__ hw, const float* __restrict__ hb,
    float* __restrict__ out)
{
    __shared__ float s_g[HD];
    const int b = blockIdx.y;
    const int p = blockIdx.x * 256 + threadIdx.x;
    if (threadIdx.x < HD) s_g[threadIdx.x] = g[(size_t)b * HD + threadIdx.x];
    __syncthreads();
    if (p >= PROP) return;
    float acc = hb[p];
    for (int k = 0; k < HD; ++k) acc += s_g[k] * hw[(size_t)k * PROP + p];
    out[(size_t)b * PROP + p] = acc;
}

extern "C" void kernel_launch(void* const* d_in, const int* in_sizes, int n_in,
                              void* d_out, int out_size, void* d_ws, size_t ws_size,
                              hipStream_t stream)
{
    const float* x        = (const float*)d_in[0];
    const float* pos_in   = (const float*)d_in[1];
    const float* eattr    = (const float*)d_in[2];
    const int*   ei       = (const int*)d_in[3];
    const int*   batch    = (const int*)d_in[4];
    const float* emb_in_w = (const float*)d_in[5];
    const float* emb_in_b = (const float*)d_in[6];
    const float* emb_out_w= (const float*)d_in[7];
    const float* emb_out_b= (const float*)d_in[8];
    const float* ew1 = (const float*)d_in[9];
    const float* eb1 = (const float*)d_in[10];
    const float* ew2 = (const float*)d_in[11];
    const float* eb2 = (const float*)d_in[12];
    const float* nw1 = (const float*)d_in[13];
    const float* nb1 = (const float*)d_in[14];
    const float* nw2 = (const float*)d_in[15];
    const float* nb2 = (const float*)d_in[16];
    const float* cw1 = (const float*)d_in[17];
    const float* cb1 = (const float*)d_in[18];
    const float* cw2 = (const float*)d_in[19];
    const float* rw1 = (const float*)d_in[20];
    const float* rb1 = (const float*)d_in[21];
    const float* rw2 = (const float*)d_in[22];
    const float* rb2 = (const float*)d_in[23];
    const float* hw  = (const float*)d_in[24];
    const float* hb  = (const float*)d_in[25];
    float* out = (float*)d_out;
    (void)ws_size;

    const int N = in_sizes[0] / 64;     // 20000
    const int E = in_sizes[2] / 16;     // 160000
    const int B = out_size / PROP;      // 1024

    // ---- workspace carve-up (f32, then bf16, then int) ----
    float* wsf = (float*)d_ws;
    float* pos_cur = wsf;   wsf += (size_t)N * 3;
    float* pos_agg = wsf;   wsf += (size_t)N * 3;
    float* h       = wsf;   wsf += (size_t)N * HD;
    float* agg     = wsf;   wsf += (size_t)N * HD;
    float* g       = wsf;   wsf += (size_t)B * HD;
    wsf += (4 - (((size_t)(wsf - (float*)d_ws)) & 3)) & 3;   // 16B align
    unsigned short* apre  = (unsigned short*)wsf;
    unsigned short* w1nc  = apre  + (size_t)N * 256;
    unsigned short* wattr = w1nc  + (size_t)4 * 256 * 128;
    unsigned short* wt2   = wattr + (size_t)4 * 128 * 32;
    unsigned short* cwt1  = wt2   + (size_t)4 * 128 * 128;
    unsigned short* nw1t  = cwt1  + (size_t)4 * 128 * 128;
    unsigned short* nw2t  = nw1t  + (size_t)4 * 128 * 256;
    int* ip   = (int*)(nw2t + (size_t)4 * 128 * 128);
    unsigned* g_enc = (unsigned*)ip;  ip += (size_t)B * HD;
    int* cnt_i = ip;  ip += N;
    int* rp    = ip;  ip += N + 1;
    int* wp    = ip;  ip += N;
    int* perm  = ip;  ip += E;

    // ---- weight prep ----
    prep_w1nc<<<(4 * 256 * 128 + 255) / 256, 256, 0, stream>>>(ew1, w1nc);
    prep_wattr<<<(4 * 128 * 32 + 255) / 256, 256, 0, stream>>>(ew1, wattr);
    prep_t<<<(4 * 128 * 128 + 255) / 256, 256, 0, stream>>>(ew2, wt2, 128);
    prep_t<<<(4 * 128 * 128 + 255) / 256, 256, 0, stream>>>(cw1, cwt1, 128);
    prep_t<<<(4 * 128 * 256 + 255) / 256, 256, 0, stream>>>(nw1, nw1t, 256);
    prep_t<<<(4 * 128 * 128 + 255) / 256, 256, 0, stream>>>(nw2, nw2t, 128);

    // ---- CSR build ----
    hipMemsetAsync(cnt_i, 0, (size_t)N * sizeof(int), stream);
    counti_kernel<<<(E + 255) / 256, 256, 0, stream>>>(ei, cnt_i, E);
    scan_kernel<<<1, 1024, 0, stream>>>(cnt_i, rp, wp, N);
    scatter_kernel<<<(E + 255) / 256, 256, 0, stream>>>(ei, wp, perm, E);

    hipMemcpyAsync(pos_cur, pos_in, (size_t)N * 3 * sizeof(float),
                   hipMemcpyDeviceToDevice, stream);
    emb_kernel<<<(N + NPB - 1) / NPB, 128, 0, stream>>>(x, emb_in_w, emb_in_b, h, N);

    const int nblk = (N + 63) / 64;
    for (int l = 0; l < 4; ++l) {
        node_pre_kernel<<<nblk, 256, 0, stream>>>(
            h, w1nc + (size_t)l * 256 * 128, eb1 + (size_t)l * HD, apre, N);
        hipMemsetAsync(agg, 0, (size_t)N * HD * sizeof(float), stream);
        hipMemsetAsync(pos_agg, 0, (size_t)N * 3 * sizeof(float), stream);
        edge_mfma_kernel<<<(E + EB - 1) / EB, 256, 0, stream>>>(
            pos_cur, apre, eattr, ei, perm,
            wattr + (size_t)l * 128 * 32,
            wt2  + (size_t)l * 128 * 128, eb2 + (size_t)l * HD,
            cwt1 + (size_t)l * 128 * 128, cb1 + (size_t)l * HD,
            cw2 + (size_t)l * HD,
            agg, pos_agg, E);
        posupd_kernel<<<(N * 3 + 255) / 256, 256, 0, stream>>>(pos_cur, pos_agg, rp, N);
        node_mfma_kernel<<<nblk, 256, 0, stream>>>(
            h, agg,
            nw1t + (size_t)l * 128 * 256, nb1 + (size_t)l * HD,
            nw2t + (size_t)l * 128 * 128, nb2 + (size_t)l * HD, N);
    }

    ginit_kernel<<<(B * HD + 255) / 256, 256, 0, stream>>>(g_enc, B * HD);
    embout_segmax_kernel<<<(N + NPB - 1) / NPB, 128, 0, stream>>>(
        h, emb_out_w, emb_out_b, batch, g_enc, N);
    resblock_kernel<<<B, 128, 0, stream>>>(g_enc, rw1, rb1, rw2, rb2, g);
    head_kernel<<<dim3((PROP + 255) / 256, B), 256, 0, stream>>>(g, hw, hb, out);
}